// Round 17
// baseline (486.811 us; speedup 1.0000x reference)
//
#include <hip/hip_runtime.h>
#include <hip/hip_bf16.h>

#define S_LEN 2048
#define NH 16
#define HD 64
#define DM 1024

typedef float f32x4 __attribute__((ext_vector_type(4)));
typedef unsigned u32x4 __attribute__((ext_vector_type(4)));
typedef unsigned u32x2 __attribute__((ext_vector_type(2)));
typedef __bf16 bf16x8 __attribute__((ext_vector_type(8)));

#define BAR() __builtin_amdgcn_s_barrier()

__device__ __forceinline__ unsigned short f2bf(float f) {
  union { float f; unsigned u; } v; v.f = f;
  unsigned r = v.u + 0x7fffu + ((v.u >> 16) & 1u);
  return (unsigned short)(r >> 16);
}

__device__ __forceinline__ unsigned pack2bf(float lo, float hi) {
  return (unsigned)f2bf(lo) | ((unsigned)f2bf(hi) << 16);
}

__device__ __forceinline__ void load_lds16(const void* g, void* l) {
  __builtin_amdgcn_global_load_lds((const __attribute__((address_space(1))) void*)g,
                                   (__attribute__((address_space(3))) void*)l, 16, 0, 0);
}

// Fused prep: blocks [0,12288) convert Q/K/V fp32->bf16; blocks [12288,16384)
// transpose+convert the 4 weight matrices (32x32 tiles).
__global__ __launch_bounds__(256) void prep_kernel(const float* __restrict__ Qi,
                                                   const float* __restrict__ Ki,
                                                   const float* __restrict__ Vi,
                                                   unsigned short* __restrict__ Qb,
                                                   unsigned short* __restrict__ Kb,
                                                   unsigned short* __restrict__ Vb,
                                                   const float* __restrict__ Wq,
                                                   const float* __restrict__ Wk,
                                                   const float* __restrict__ Wv,
                                                   const float* __restrict__ Wo,
                                                   unsigned short* __restrict__ Wtq,
                                                   unsigned short* __restrict__ Wtk,
                                                   unsigned short* __restrict__ Wtv,
                                                   unsigned short* __restrict__ Wto) {
  __shared__ float t[32][33];
  const int bid = blockIdx.x;
  if (bid < 12288) {
    int sel = bid >> 12;
    int i = (bid & 4095) * 256 + threadIdx.x;
    const float* in = sel == 0 ? Qi : (sel == 1 ? Ki : Vi);
    unsigned short* out = sel == 0 ? Qb : (sel == 1 ? Kb : Vb);
    float4 v = reinterpret_cast<const float4*>(in)[i];
    ushort4 o;
    o.x = f2bf(v.x); o.y = f2bf(v.y); o.z = f2bf(v.z); o.w = f2bf(v.w);
    reinterpret_cast<ushort4*>(out)[i] = o;
  } else {
    int r = bid - 12288;
    int wi = r >> 10, ti = r & 1023;
    const float* W = wi == 0 ? Wq : (wi == 1 ? Wk : (wi == 2 ? Wv : Wo));
    unsigned short* Wt = wi == 0 ? Wtq : (wi == 1 ? Wtk : (wi == 2 ? Wtv : Wto));
    int bx = (ti & 31) * 32;  // n base
    int by = (ti >> 5) * 32;  // k base
    int tx = threadIdx.x & 31, ty = threadIdx.x >> 5;
    for (int i = ty; i < 32; i += 8) t[i][tx] = W[(size_t)(by + i) * DM + bx + tx];
    __syncthreads();
    for (int i = ty; i < 32; i += 8) Wt[(size_t)(bx + i) * DM + by + tx] = f2bf(t[tx][i]);
  }
}

// All three projection GEMMs in one launch: grid (32,8,3), 128x128 tile.
__global__ __launch_bounds__(256) void gemm_qkv(const unsigned short* __restrict__ Qb,
                                                const unsigned short* __restrict__ Kb,
                                                const unsigned short* __restrict__ Vb,
                                                const unsigned short* __restrict__ Wtq,
                                                const unsigned short* __restrict__ Wtk,
                                                const unsigned short* __restrict__ Wtv,
                                                const float* __restrict__ bq,
                                                const float* __restrict__ bk,
                                                const float* __restrict__ bv,
                                                unsigned short* __restrict__ Qhd,
                                                unsigned short* __restrict__ Khd,
                                                unsigned short* __restrict__ Vtd) {
  constexpr int K = 1024;
  __shared__ unsigned short Al[128 * 32];
  __shared__ unsigned short Bl[128 * 32];
  const int z = blockIdx.z;
  const unsigned short* A = z == 0 ? Qb : (z == 1 ? Kb : Vb);
  const unsigned short* Bt = z == 0 ? Wtq : (z == 1 ? Wtk : Wtv);
  const float* bias = z == 0 ? bq : (z == 1 ? bk : bv);
  unsigned short* C = z == 0 ? Qhd : (z == 1 ? Khd : Vtd);
  const int tid = threadIdx.x;
  const int w = tid >> 6, l = tid & 63;
  const int m0 = blockIdx.x * 128, n0 = blockIdx.y * 128;
  const int wr = (w >> 1) * 64, wc = (w & 1) * 64;
  const int lr = l & 15, lk = l >> 4;
  f32x4 acc[4][4] = {};
  for (int kt = 0; kt < K; kt += 32) {
#pragma unroll
    for (int i = 0; i < 2; ++i) {
      int seg = i * 256 + tid;
      int row = seg >> 2, ks = (seg & 3) * 8;
      load_lds16(A + (size_t)(m0 + row) * K + kt + ks, Al + seg * 8);
      load_lds16(Bt + (size_t)(n0 + row) * K + kt + ks, Bl + seg * 8);
    }
    __syncthreads();
    bf16x8 af[4], bfr[4];
#pragma unroll
    for (int t = 0; t < 4; ++t) af[t] = *(const bf16x8*)(Al + (wr + t * 16 + lr) * 32 + lk * 8);
#pragma unroll
    for (int t = 0; t < 4; ++t) bfr[t] = *(const bf16x8*)(Bl + (wc + t * 16 + lr) * 32 + lk * 8);
#pragma unroll
    for (int i = 0; i < 4; ++i)
#pragma unroll
      for (int j = 0; j < 4; ++j)
        acc[i][j] = __builtin_amdgcn_mfma_f32_16x16x32_bf16(af[i], bfr[j], acc[i][j], 0, 0, 0);
    __syncthreads();
  }
  const int drow = lk * 4, dcol = lr;
  if (z < 2) {
#pragma unroll
    for (int i = 0; i < 4; ++i)
#pragma unroll
      for (int j = 0; j < 4; ++j) {
        int n = n0 + wc + j * 16 + dcol;
        float bv_ = bias[n];
        int h = n >> 6, d = n & 63;
#pragma unroll
        for (int r = 0; r < 4; ++r) {
          int m = m0 + wr + i * 16 + drow + r;
          int b = m >> 11, s = m & 2047;
          C[((size_t)(b * NH + h) * S_LEN + s) * HD + d] = f2bf(acc[i][j][r] + bv_);
        }
      }
  } else {
#pragma unroll
    for (int i = 0; i < 4; ++i) {
      int m = m0 + wr + i * 16 + drow;
      int b = m >> 11, s = m & 2047;
#pragma unroll
      for (int j = 0; j < 4; ++j) {
        int n = n0 + wc + j * 16 + dcol;
        float bv_ = bias[n];
        int h = n >> 6, d = n & 63;
        ushort4 o;
        o.x = f2bf(acc[i][j][0] + bv_);
        o.y = f2bf(acc[i][j][1] + bv_);
        o.z = f2bf(acc[i][j][2] + bv_);
        o.w = f2bf(acc[i][j][3] + bv_);
        *reinterpret_cast<ushort4*>(C + ((size_t)(b * NH + h) * HD + d) * S_LEN + s) = o;
      }
    }
  }
}

// Output projection GEMM (fp32 rowmajor out), 128x64 tile, grid (32,16).
__global__ __launch_bounds__(256) void gemm_out(const unsigned short* __restrict__ A,
                                                const unsigned short* __restrict__ Bt,
                                                const float* __restrict__ bias,
                                                float* __restrict__ C) {
  constexpr int K = 1024;
  constexpr int N = 1024;
  __shared__ unsigned short Al[128 * 32];
  __shared__ unsigned short Bl[64 * 32];
  const int tid = threadIdx.x;
  const int w = tid >> 6, l = tid & 63;
  const int m0 = blockIdx.x * 128, n0 = blockIdx.y * 64;
  const int wr = (w >> 1) * 64, wc = (w & 1) * 32;
  const int lr = l & 15, lk = l >> 4;
  f32x4 acc[4][2] = {};
  for (int kt = 0; kt < K; kt += 32) {
#pragma unroll
    for (int i = 0; i < 2; ++i) {
      int seg = i * 256 + tid;
      int row = seg >> 2, ks = (seg & 3) * 8;
      load_lds16(A + (size_t)(m0 + row) * K + kt + ks, Al + seg * 8);
    }
    {
      int row = tid >> 2, ks = (tid & 3) * 8;
      load_lds16(Bt + (size_t)(n0 + row) * K + kt + ks, Bl + tid * 8);
    }
    __syncthreads();
    bf16x8 af[4], bfr[2];
#pragma unroll
    for (int t = 0; t < 4; ++t) af[t] = *(const bf16x8*)(Al + (wr + t * 16 + lr) * 32 + lk * 8);
#pragma unroll
    for (int t = 0; t < 2; ++t) bfr[t] = *(const bf16x8*)(Bl + (wc + t * 16 + lr) * 32 + lk * 8);
#pragma unroll
    for (int i = 0; i < 4; ++i)
#pragma unroll
      for (int j = 0; j < 2; ++j)
        acc[i][j] = __builtin_amdgcn_mfma_f32_16x16x32_bf16(af[i], bfr[j], acc[i][j], 0, 0, 0);
    __syncthreads();
  }
  const int drow = lk * 4, dcol = lr;
#pragma unroll
  for (int i = 0; i < 4; ++i)
#pragma unroll
    for (int j = 0; j < 2; ++j) {
      int n = n0 + wc + j * 16 + dcol;
      float bv = bias[n];
#pragma unroll
      for (int r = 0; r < 4; ++r) {
        int m = m0 + wr + i * 16 + drow + r;
        C[(size_t)m * N + n] = acc[i][j][r] + bv;
      }
    }
}

// ---------------------------------------------------------------------------
// Fused attention, BARRIER-FREE phases (K/V are single-use and L2-resident
// under XCD clustering -> no LDS staging, per guide Common-mistake #7):
//  phase 1: register-direct K and V; lsum + UNNORMALIZED PV -> ctx. P remap
//           through a per-wave 2KB LDS buffer (single-buffered: per-wave DS
//           ops are in-order, so next iter's writes can't pass this iter's
//           reads). No block barriers at all.
//  phase 2: register-direct K, p=exp(s)*linv, coalesced attn store via
//           per-wave 8KB LDS tile, 8 NT stores of 2 rows x 512B per flush.
// One s_barrier between phases (phase-2 tiles alias other waves' P buffers).
// Swapped QK^T (A=K,B=Q): lane (lr,lk) holds S[k=t*64+st*16+lk*4+r][q=q0w+lr].
// ---------------------------------------------------------------------------
#define LOADK_R(T)                                                             \
  _Pragma("unroll") for (int st = 0; st < 4; ++st) {                           \
    const unsigned short* kp = Kbh + (size_t)((T) * 64 + st * 16 + lr) * HD + lk * 8; \
    kf0[st] = *(const bf16x8*)kp;                                              \
    kf1[st] = *(const bf16x8*)(kp + 32);                                       \
  }

#define QKT_R()                                                                \
  _Pragma("unroll") for (int st = 0; st < 4; ++st) {                           \
    f32x4 a = {};                                                              \
    a = __builtin_amdgcn_mfma_f32_16x16x32_bf16(kf0[st], qf0, a, 0, 0, 0);     \
    a = __builtin_amdgcn_mfma_f32_16x16x32_bf16(kf1[st], qf1, a, 0, 0, 0);     \
    acc[st] = a;                                                               \
  }

#define MASKADJ4(T)                                                            \
  _Pragma("unroll") for (int st = 0; st < 4; ++st) {                           \
    uchar4 m4 = *(const uchar4*)(mrow + (T) * 64 + st * 16 + lk * 4);          \
    if (m4.x) acc[st][0] = -8e9f;                                              \
    if (m4.y) acc[st][1] = -8e9f;                                              \
    if (m4.z) acc[st][2] = -8e9f;                                              \
    if (m4.w) acc[st][3] = -8e9f;                                              \
  }

#define MASK_PREPASS()                                                         \
  unsigned maskbits = 0;                                                       \
  _Pragma("unroll") for (int g4 = 0; g4 < 4; ++g4) {                           \
    unsigned mm[8];                                                            \
    const char* mp = (const char*)mrow + g4 * 512 + lk * 16;                   \
    _Pragma("unroll") for (int q8 = 0; q8 < 8; ++q8) {                         \
      u32x4 v = __builtin_nontemporal_load((const u32x4*)(mp + q8 * 64));      \
      mm[q8] = v.x | v.y | v.z | v.w;                                          \
    }                                                                          \
    _Pragma("unroll") for (int q8 = 0; q8 < 8; ++q8)                           \
      if (__any(mm[q8] != 0)) maskbits |= 1u << (g4 * 8 + q8);                 \
  }

__global__ __launch_bounds__(512, 4) void attn_fused_kernel(const unsigned short* __restrict__ Qh,
                                                            const unsigned short* __restrict__ Kh,
                                                            const unsigned short* __restrict__ Vt,
                                                            const unsigned char* __restrict__ mask,
                                                            float* __restrict__ attn_out,
                                                            unsigned short* __restrict__ ctx) {
  __shared__ char lds[65536];  // ph1: per-wave 2KB Premap @0 (16KB)
                               // ph2: per-wave 8KB P-store tiles @0 (64KB)
  const int tid = threadIdx.x;
  const int w = tid >> 6, l = tid & 63;
  const int lr = l & 15, lk = l >> 4;
  const int L = blockIdx.x;
  const int g = L & 7, j = L >> 3;
  const int bh = g * 4 + (j & 3);
  const int qt = j >> 2;
  const int q0w = qt * 128 + w * 16;
  const int b = bh >> 4, h = bh & 15;
  const unsigned short* Qbh = Qh + (size_t)bh * S_LEN * HD;
  const unsigned short* Kbh = Kh + (size_t)bh * S_LEN * HD;
  const unsigned short* Vbh = Vt + (size_t)bh * HD * S_LEN;
  const unsigned char* mrow = mask + (size_t)b * S_LEN * S_LEN + (size_t)(q0w + lr) * S_LEN;
  char* const abase = (char*)(attn_out + ((size_t)bh * S_LEN + q0w) * S_LEN);

  bf16x8 qf0 = *(const bf16x8*)(Qbh + (q0w + lr) * HD + lk * 8);
  bf16x8 qf1 = *(const bf16x8*)(Qbh + (q0w + lr) * HD + 32 + lk * 8);
  const int sw = (lr & 7) << 4;
  const float sc = 0.125f;

  MASK_PREPASS()

  f32x4 acc[4];
  bf16x8 kf0[4], kf1[4];
  f32x4 cacc[4] = {};
  float tsum = 0.f;

  // ---- phase 1: register-direct K/V, lsum + unnormalized PV, no barriers ----
  char* const Pw = lds + w * 2048;
  for (int t = 0; t < 32; ++t) {
    LOADK_R(t)
    QKT_R()
    if (maskbits & (1u << t)) { MASKADJ4(t) }
    unsigned pk0[4], pk1[4];
#pragma unroll
    for (int st = 0; st < 4; ++st) {
      float p0 = __expf(acc[st][0] * sc);
      float p1 = __expf(acc[st][1] * sc);
      float p2 = __expf(acc[st][2] * sc);
      float p3 = __expf(acc[st][3] * sc);
      tsum += p0 + p1 + p2 + p3;
      pk0[st] = pack2bf(p0, p1);
      pk1[st] = pack2bf(p2, p3);
    }
#pragma unroll
    for (int st = 0; st < 4; ++st) {
      u32x2 pv;
      pv.x = pk0[st];
      pv.y = pk1[st];
      *(u32x2*)(Pw + lr * 128 + ((st * 32 + lk * 8) ^ sw)) = pv;
    }
    asm volatile("s_waitcnt lgkmcnt(0)" ::: "memory");
    __builtin_amdgcn_sched_barrier(0);
#pragma unroll
    for (int c = 0; c < 2; ++c) {
      bf16x8 af = *(const bf16x8*)(Pw + lr * 128 + ((c * 64 + lk * 16) ^ sw));
#pragma unroll
      for (int dt = 0; dt < 4; ++dt) {
        bf16x8 vb = *(const bf16x8*)(Vbh + (size_t)(dt * 16 + lr) * S_LEN +
                                     t * 64 + c * 32 + lk * 8);
        cacc[dt] = __builtin_amdgcn_mfma_f32_16x16x32_bf16(af, vb, cacc[dt], 0, 0, 0);
      }
    }
  }
  tsum += __shfl_xor(tsum, 16, 64);
  tsum += __shfl_xor(tsum, 32, 64);
  const float linv = 1.0f / tsum;

  // ctx (normalize here): lane (lr,lk) holds ctx[q=q0w+lk*4+r][d=dt*16+lr]
#pragma unroll
  for (int dt = 0; dt < 4; ++dt)
#pragma unroll
    for (int r = 0; r < 4; ++r)
      ctx[(size_t)(b * S_LEN + q0w + lk * 4 + r) * DM + h * HD + dt * 16 + lr] =
          f2bf(cacc[dt][r] * linv);

  // ---- phase 2: coalesced attn store (per-wave 8KB tiles) ----
  BAR();  // phase-2 tiles alias other waves' phase-1 P buffers
  char* const Pw2 = lds + w * 8192;
  const int swp = lr << 4;
  for (int tt = 0; tt < 16; ++tt) {
#pragma unroll
    for (int half = 0; half < 2; ++half) {
      const int t = tt * 2 + half;
      LOADK_R(t)
      QKT_R()
      if (maskbits & (1u << t)) { MASKADJ4(t) }
      // P tile write: lane (lr,lk) holds row lr, bytes half*256+st*64+lk*16
#pragma unroll
      for (int st = 0; st < 4; ++st) {
        f32x4 p;
        p.x = __expf(acc[st][0] * sc) * linv;
        p.y = __expf(acc[st][1] * sc) * linv;
        p.z = __expf(acc[st][2] * sc) * linv;
        p.w = __expf(acc[st][3] * sc) * linv;
        *(f32x4*)(Pw2 + lr * 512 + ((half * 256 + st * 64 + lk * 16) ^ swp)) = p;
      }
    }
    asm volatile("s_waitcnt lgkmcnt(0)" ::: "memory");
    __builtin_amdgcn_sched_barrier(0);
    // 8 coalesced NT stores: inst s covers rows {2s, 2s+1} x 512B contiguous.
#pragma unroll
    for (int s = 0; s < 8; ++s) {
      const int row = s * 2 + (l >> 5);
      const int ch = (l & 31) * 16;
      f32x4 v = *(const f32x4*)(Pw2 + row * 512 + (ch ^ (row << 4)));
      __builtin_nontemporal_store(v, (f32x4*)(abase + (size_t)row * 8192 + tt * 512 + ch));
    }
  }
}

// residual + LayerNorm: out = LN(pre + Qin) * gamma + beta, rows of 1024
__global__ __launch_bounds__(256) void ln_kernel(const float* __restrict__ pre,
                                                 const float* __restrict__ Qin,
                                                 const float* __restrict__ gamma,
                                                 const float* __restrict__ beta,
                                                 float* __restrict__ out) {
  __shared__ float red[4];
  const int row = blockIdx.x;
  const int tid = threadIdx.x;
  const int wv = tid >> 6, l = tid & 63;
  const float4 a = reinterpret_cast<const float4*>(pre + (size_t)row * DM)[tid];
  const float4 q = reinterpret_cast<const float4*>(Qin + (size_t)row * DM)[tid];
  float x0 = a.x + q.x, x1 = a.y + q.y, x2 = a.z + q.z, x3 = a.w + q.w;
  float s = x0 + x1 + x2 + x3;
#pragma unroll
  for (int off = 32; off >= 1; off >>= 1) s += __shfl_xor(s, off, 64);
  if (l == 0) red[wv] = s;
  __syncthreads();
  float mean = (red[0] + red[1] + red[2] + red[3]) * (1.0f / 1024.0f);
  __syncthreads();
  float d0 = x0 - mean, d1 = x1 - mean, d2 = x2 - mean, d3 = x3 - mean;
  float s2 = d0 * d0 + d1 * d1 + d2 * d2 + d3 * d3;
#pragma unroll
  for (int off = 32; off >= 1; off >>= 1) s2 += __shfl_xor(s2, off, 64);
  if (l == 0) red[wv] = s2;
  __syncthreads();
  float var = (red[0] + red[1] + red[2] + red[3]) * (1.0f / 1024.0f);
  float rstd = rsqrtf(var + 1e-5f);
  const float4 g = reinterpret_cast<const float4*>(gamma)[tid];
  const float4 bt = reinterpret_cast<const float4*>(beta)[tid];
  float4 o;
  o.x = d0 * rstd * g.x + bt.x;
  o.y = d1 * rstd * g.y + bt.y;
  o.z = d2 * rstd * g.z + bt.z;
  o.w = d3 * rstd * g.w + bt.w;
  reinterpret_cast<float4*>(out + (size_t)row * DM)[tid] = o;
}

extern "C" void kernel_launch(void* const* d_in, const int* in_sizes, int n_in,
                              void* d_out, int out_size, void* d_ws, size_t ws_size,
                              hipStream_t stream) {
  const float* Qi = (const float*)d_in[0];
  const float* Ki = (const float*)d_in[1];
  const float* Vi = (const float*)d_in[2];
  const unsigned char* mask = (const unsigned char*)d_in[3];
  const float* Wq = (const float*)d_in[4];
  const float* bq = (const float*)d_in[5];
  const float* Wk = (const float*)d_in[6];
  const float* bk = (const float*)d_in[7];
  const float* Wv = (const float*)d_in[8];
  const float* bv = (const float*)d_in[9];
  const float* Wo = (const float*)d_in[10];
  const float* bo = (const float*)d_in[11];
  const float* gamma = (const float*)d_in[12];
  const float* beta = (const float*)d_in[13];

  char* ws = (char*)d_ws;
  unsigned short* Qb = (unsigned short*)(ws);            // [4096][1024] bf16
  unsigned short* Kb = Qb + 4194304;
  unsigned short* Vb = Qb + 2 * 4194304;
  unsigned short* Wtq = (unsigned short*)(ws + 25165824);  // [n][k] bf16 x4
  unsigned short* Wtk = Wtq + 1048576;
  unsigned short* Wtv = Wtq + 2 * 1048576;
  unsigned short* Wto = Wtq + 3 * 1048576;
  unsigned short* Qhd = (unsigned short*)(ws + 33554432);  // [B,H,S,64] bf16
  unsigned short* Khd = (unsigned short*)(ws + 41943040);  // [B,H,S,64] bf16
  unsigned short* Vtd = (unsigned short*)(ws + 50331648);  // [B,H,64,S] bf16
  unsigned short* ctx = (unsigned short*)(ws);             // reuse Qb region
  float* preLN = (float*)(ws + 8388608);                   // reuse Kb/Vb region

  float* out0 = (float*)d_out;
  float* attn = out0 + 4194304;

  prep_kernel<<<16384, 256, 0, stream>>>(Qi, Ki, Vi, Qb, Kb, Vb,
                                         Wq, Wk, Wv, Wo, Wtq, Wtk, Wtv, Wto);
  dim3 gqkv(32, 8, 3);
  gemm_qkv<<<gqkv, 256, 0, stream>>>(Qb, Kb, Vb, Wtq, Wtk, Wtv,
                                     bq, bk, bv, Qhd, Khd, Vtd);
  attn_fused_kernel<<<512, 512, 0, stream>>>(Qhd, Khd, Vtd, mask, attn, ctx);
  dim3 gg(32, 16);
  gemm_out<<<gg, 256, 0, stream>>>(ctx, Wto, bo, preLN);
  ln_kernel<<<4096, 256, 0, stream>>>(preLN, Qi, gamma, beta, out0);
}

// Round 18
// 300.079 us; speedup vs baseline: 1.6223x; 1.6223x over previous
//
#include <hip/hip_runtime.h>
#include <hip/hip_bf16.h>

#define S_LEN 2048
#define NH 16
#define HD 64
#define DM 1024

typedef float f32x4 __attribute__((ext_vector_type(4)));
typedef unsigned u32x4 __attribute__((ext_vector_type(4)));
typedef unsigned u32x2 __attribute__((ext_vector_type(2)));
typedef __bf16 bf16x8 __attribute__((ext_vector_type(8)));

#define BAR() __builtin_amdgcn_s_barrier()
#define VMCNT(N) asm volatile("s_waitcnt vmcnt(" #N ")" ::: "memory")

__device__ __forceinline__ unsigned short f2bf(float f) {
  union { float f; unsigned u; } v; v.f = f;
  unsigned r = v.u + 0x7fffu + ((v.u >> 16) & 1u);
  return (unsigned short)(r >> 16);
}

__device__ __forceinline__ unsigned pack2bf(float lo, float hi) {
  return (unsigned)f2bf(lo) | ((unsigned)f2bf(hi) << 16);
}

__device__ __forceinline__ void load_lds16(const void* g, void* l) {
  __builtin_amdgcn_global_load_lds((const __attribute__((address_space(1))) void*)g,
                                   (__attribute__((address_space(3))) void*)l, 16, 0, 0);
}

// Fused prep: blocks [0,12288) convert Q/K/V fp32->bf16; blocks [12288,16384)
// transpose+convert the 4 weight matrices (32x32 tiles).
__global__ __launch_bounds__(256) void prep_kernel(const float* __restrict__ Qi,
                                                   const float* __restrict__ Ki,
                                                   const float* __restrict__ Vi,
                                                   unsigned short* __restrict__ Qb,
                                                   unsigned short* __restrict__ Kb,
                                                   unsigned short* __restrict__ Vb,
                                                   const float* __restrict__ Wq,
                                                   const float* __restrict__ Wk,
                                                   const float* __restrict__ Wv,
                                                   const float* __restrict__ Wo,
                                                   unsigned short* __restrict__ Wtq,
                                                   unsigned short* __restrict__ Wtk,
                                                   unsigned short* __restrict__ Wtv,
                                                   unsigned short* __restrict__ Wto) {
  __shared__ float t[32][33];
  const int bid = blockIdx.x;
  if (bid < 12288) {
    int sel = bid >> 12;
    int i = (bid & 4095) * 256 + threadIdx.x;
    const float* in = sel == 0 ? Qi : (sel == 1 ? Ki : Vi);
    unsigned short* out = sel == 0 ? Qb : (sel == 1 ? Kb : Vb);
    float4 v = reinterpret_cast<const float4*>(in)[i];
    ushort4 o;
    o.x = f2bf(v.x); o.y = f2bf(v.y); o.z = f2bf(v.z); o.w = f2bf(v.w);
    reinterpret_cast<ushort4*>(out)[i] = o;
  } else {
    int r = bid - 12288;
    int wi = r >> 10, ti = r & 1023;
    const float* W = wi == 0 ? Wq : (wi == 1 ? Wk : (wi == 2 ? Wv : Wo));
    unsigned short* Wt = wi == 0 ? Wtq : (wi == 1 ? Wtk : (wi == 2 ? Wtv : Wto));
    int bx = (ti & 31) * 32;  // n base
    int by = (ti >> 5) * 32;  // k base
    int tx = threadIdx.x & 31, ty = threadIdx.x >> 5;
    for (int i = ty; i < 32; i += 8) t[i][tx] = W[(size_t)(by + i) * DM + bx + tx];
    __syncthreads();
    for (int i = ty; i < 32; i += 8) Wt[(size_t)(bx + i) * DM + by + tx] = f2bf(t[tx][i]);
  }
}

// All three projection GEMMs in one launch: grid (32,8,3), 128x128 tile.
// z=0: Q->Qhd (head-major), z=1: K->Khd (head-major), z=2: V->Vtd (transposed).
__global__ __launch_bounds__(256) void gemm_qkv(const unsigned short* __restrict__ Qb,
                                                const unsigned short* __restrict__ Kb,
                                                const unsigned short* __restrict__ Vb,
                                                const unsigned short* __restrict__ Wtq,
                                                const unsigned short* __restrict__ Wtk,
                                                const unsigned short* __restrict__ Wtv,
                                                const float* __restrict__ bq,
                                                const float* __restrict__ bk,
                                                const float* __restrict__ bv,
                                                unsigned short* __restrict__ Qhd,
                                                unsigned short* __restrict__ Khd,
                                                unsigned short* __restrict__ Vtd) {
  constexpr int K = 1024;
  __shared__ unsigned short Al[128 * 32];
  __shared__ unsigned short Bl[128 * 32];
  const int z = blockIdx.z;
  const unsigned short* A = z == 0 ? Qb : (z == 1 ? Kb : Vb);
  const unsigned short* Bt = z == 0 ? Wtq : (z == 1 ? Wtk : Wtv);
  const float* bias = z == 0 ? bq : (z == 1 ? bk : bv);
  unsigned short* C = z == 0 ? Qhd : (z == 1 ? Khd : Vtd);
  const int tid = threadIdx.x;
  const int w = tid >> 6, l = tid & 63;
  const int m0 = blockIdx.x * 128, n0 = blockIdx.y * 128;
  const int wr = (w >> 1) * 64, wc = (w & 1) * 64;
  const int lr = l & 15, lk = l >> 4;
  f32x4 acc[4][4] = {};
  for (int kt = 0; kt < K; kt += 32) {
#pragma unroll
    for (int i = 0; i < 2; ++i) {
      int seg = i * 256 + tid;
      int row = seg >> 2, ks = (seg & 3) * 8;
      load_lds16(A + (size_t)(m0 + row) * K + kt + ks, Al + seg * 8);
      load_lds16(Bt + (size_t)(n0 + row) * K + kt + ks, Bl + seg * 8);
    }
    __syncthreads();
    bf16x8 af[4], bfr[4];
#pragma unroll
    for (int t = 0; t < 4; ++t) af[t] = *(const bf16x8*)(Al + (wr + t * 16 + lr) * 32 + lk * 8);
#pragma unroll
    for (int t = 0; t < 4; ++t) bfr[t] = *(const bf16x8*)(Bl + (wc + t * 16 + lr) * 32 + lk * 8);
#pragma unroll
    for (int i = 0; i < 4; ++i)
#pragma unroll
      for (int j = 0; j < 4; ++j)
        acc[i][j] = __builtin_amdgcn_mfma_f32_16x16x32_bf16(af[i], bfr[j], acc[i][j], 0, 0, 0);
    __syncthreads();
  }
  const int drow = lk * 4, dcol = lr;
  if (z < 2) {
#pragma unroll
    for (int i = 0; i < 4; ++i)
#pragma unroll
      for (int j = 0; j < 4; ++j) {
        int n = n0 + wc + j * 16 + dcol;
        float bv_ = bias[n];
        int h = n >> 6, d = n & 63;
#pragma unroll
        for (int r = 0; r < 4; ++r) {
          int m = m0 + wr + i * 16 + drow + r;
          int b = m >> 11, s = m & 2047;
          C[((size_t)(b * NH + h) * S_LEN + s) * HD + d] = f2bf(acc[i][j][r] + bv_);
        }
      }
  } else {
#pragma unroll
    for (int i = 0; i < 4; ++i) {
      int m = m0 + wr + i * 16 + drow;
      int b = m >> 11, s = m & 2047;
#pragma unroll
      for (int j = 0; j < 4; ++j) {
        int n = n0 + wc + j * 16 + dcol;
        float bv_ = bias[n];
        int h = n >> 6, d = n & 63;
        ushort4 o;
        o.x = f2bf(acc[i][j][0] + bv_);
        o.y = f2bf(acc[i][j][1] + bv_);
        o.z = f2bf(acc[i][j][2] + bv_);
        o.w = f2bf(acc[i][j][3] + bv_);
        *reinterpret_cast<ushort4*>(C + ((size_t)(b * NH + h) * HD + d) * S_LEN + s) = o;
      }
    }
  }
}

// Output projection GEMM (fp32 rowmajor out), 128x64 tile, grid (32,16).
__global__ __launch_bounds__(256) void gemm_out(const unsigned short* __restrict__ A,
                                                const unsigned short* __restrict__ Bt,
                                                const float* __restrict__ bias,
                                                float* __restrict__ C) {
  constexpr int K = 1024;
  constexpr int N = 1024;
  __shared__ unsigned short Al[128 * 32];
  __shared__ unsigned short Bl[64 * 32];
  const int tid = threadIdx.x;
  const int w = tid >> 6, l = tid & 63;
  const int m0 = blockIdx.x * 128, n0 = blockIdx.y * 64;
  const int wr = (w >> 1) * 64, wc = (w & 1) * 32;
  const int lr = l & 15, lk = l >> 4;
  f32x4 acc[4][2] = {};
  for (int kt = 0; kt < K; kt += 32) {
#pragma unroll
    for (int i = 0; i < 2; ++i) {
      int seg = i * 256 + tid;
      int row = seg >> 2, ks = (seg & 3) * 8;
      load_lds16(A + (size_t)(m0 + row) * K + kt + ks, Al + seg * 8);
    }
    {
      int row = tid >> 2, ks = (tid & 3) * 8;
      load_lds16(Bt + (size_t)(n0 + row) * K + kt + ks, Bl + tid * 8);
    }
    __syncthreads();
    bf16x8 af[4], bfr[2];
#pragma unroll
    for (int t = 0; t < 4; ++t) af[t] = *(const bf16x8*)(Al + (wr + t * 16 + lr) * 32 + lk * 8);
#pragma unroll
    for (int t = 0; t < 2; ++t) bfr[t] = *(const bf16x8*)(Bl + (wc + t * 16 + lr) * 32 + lk * 8);
#pragma unroll
    for (int i = 0; i < 4; ++i)
#pragma unroll
      for (int j = 0; j < 2; ++j)
        acc[i][j] = __builtin_amdgcn_mfma_f32_16x16x32_bf16(af[i], bfr[j], acc[i][j], 0, 0, 0);
    __syncthreads();
  }
  const int drow = lk * 4, dcol = lr;
#pragma unroll
  for (int i = 0; i < 4; ++i)
#pragma unroll
    for (int j = 0; j < 2; ++j) {
      int n = n0 + wc + j * 16 + dcol;
      float bv = bias[n];
#pragma unroll
      for (int r = 0; r < 4; ++r) {
        int m = m0 + wr + i * 16 + drow + r;
        C[(size_t)m * N + n] = acc[i][j][r] + bv;
      }
    }
}

// ---------------------------------------------------------------------------
// Fused attention (single kernel), R16 verified structure:
//  phase 1: K+V LDS-staged (3-buffer, depth-2, counted VMCNT): lsum +
//           UNNORMALIZED PV -> ctx (normalized at end). maskbits/linv stay in
//           registers.
//  phase 2: register-direct K (L2-hot from phase 1), p=exp(s)*linv, coalesced
//           attn store: 2 k-tiles per per-wave 8KB LDS tile (reusing the
//           staging LDS), 8 NT stores of 2 rows x 512B contiguous per flush.
// NOTE (R17 lesson): with the per-iteration lgkmcnt(0)+sched_barrier(0) fence
// required by the P-remap, K/V must be staged via global_load_lds -- register-
// direct loads get trapped behind the fence and serialize on L2 latency.
// Swapped QK^T (A=K,B=Q): lane (lr,lk) holds S[k=t*64+st*16+lk*4+r][q=q0w+lr].
// ---------------------------------------------------------------------------
#define STG_K(T, BASE)                                                         \
  {                                                                            \
    int s_ = tid;                                                              \
    int row_ = s_ >> 3, cb_ = (s_ & 7) * 16;                                   \
    load_lds16((const char*)Kbh + (size_t)((T) * 64 + row_) * 128 +            \
                   (cb_ ^ ((row_ & 7) << 4)),                                  \
               (BASE) + s_ * 16);                                              \
  }

#define STG_V(T, BASE)                                                         \
  {                                                                            \
    int s_ = tid;                                                              \
    int row_ = s_ >> 3, cb_ = (s_ & 7) * 16;                                   \
    load_lds16((const char*)Vbh + (size_t)row_ * 4096 + (T) * 128 +            \
                   (cb_ ^ ((row_ & 7) << 4)),                                  \
               (BASE) + s_ * 16);                                              \
  }

#define QKT4(KPTR)                                                             \
  _Pragma("unroll") for (int st = 0; st < 4; ++st) {                           \
    const char* rp = (KPTR) + (st * 16 + lr) * 128;                            \
    bf16x8 k0 = *(const bf16x8*)(rp + a0);                                     \
    bf16x8 k1 = *(const bf16x8*)(rp + (a0 ^ 64));                              \
    f32x4 a = {};                                                              \
    a = __builtin_amdgcn_mfma_f32_16x16x32_bf16(k0, qf0, a, 0, 0, 0);          \
    a = __builtin_amdgcn_mfma_f32_16x16x32_bf16(k1, qf1, a, 0, 0, 0);          \
    acc[st] = a;                                                               \
  }

#define MASKADJ4(T)                                                            \
  _Pragma("unroll") for (int st = 0; st < 4; ++st) {                           \
    uchar4 m4 = *(const uchar4*)(mrow + (T) * 64 + st * 16 + lk * 4);          \
    if (m4.x) acc[st][0] = -8e9f;                                              \
    if (m4.y) acc[st][1] = -8e9f;                                              \
    if (m4.z) acc[st][2] = -8e9f;                                              \
    if (m4.w) acc[st][3] = -8e9f;                                              \
  }

#define MASK_PREPASS()                                                         \
  unsigned maskbits = 0;                                                       \
  _Pragma("unroll") for (int g4 = 0; g4 < 4; ++g4) {                           \
    unsigned mm[8];                                                            \
    const char* mp = (const char*)mrow + g4 * 512 + lk * 16;                   \
    _Pragma("unroll") for (int q8 = 0; q8 < 8; ++q8) {                         \
      u32x4 v = __builtin_nontemporal_load((const u32x4*)(mp + q8 * 64));      \
      mm[q8] = v.x | v.y | v.z | v.w;                                          \
    }                                                                          \
    _Pragma("unroll") for (int q8 = 0; q8 < 8; ++q8)                           \
      if (__any(mm[q8] != 0)) maskbits |= 1u << (g4 * 8 + q8);                 \
  }

__global__ __launch_bounds__(512, 4) void attn_fused_kernel(const unsigned short* __restrict__ Qh,
                                                            const unsigned short* __restrict__ Kh,
                                                            const unsigned short* __restrict__ Vt,
                                                            const unsigned char* __restrict__ mask,
                                                            float* __restrict__ attn_out,
                                                            unsigned short* __restrict__ ctx) {
  __shared__ char lds[81920];  // ph1: K 3x8KB @0, V 3x8KB @24576, Premap 8x2x2KB @49152
                               // ph2: per-wave 8KB P-store tiles @0 (64KB)
  char* const ldsK = lds;
  char* const ldsV = lds + 24576;
  const int tid = threadIdx.x;
  const int w = tid >> 6, l = tid & 63;
  const int lr = l & 15, lk = l >> 4;
  const int L = blockIdx.x;
  const int g = L & 7, j = L >> 3;
  const int bh = g * 4 + (j & 3);
  const int qt = j >> 2;
  const int q0w = qt * 128 + w * 16;
  const int b = bh >> 4, h = bh & 15;
  const unsigned short* Qbh = Qh + (size_t)bh * S_LEN * HD;
  const unsigned short* Kbh = Kh + (size_t)bh * S_LEN * HD;
  const unsigned short* Vbh = Vt + (size_t)bh * HD * S_LEN;
  const unsigned char* mrow = mask + (size_t)b * S_LEN * S_LEN + (size_t)(q0w + lr) * S_LEN;
  char* const abase = (char*)(attn_out + ((size_t)bh * S_LEN + q0w) * S_LEN);

  bf16x8 qf0 = *(const bf16x8*)(Qbh + (q0w + lr) * HD + lk * 8);
  bf16x8 qf1 = *(const bf16x8*)(Qbh + (q0w + lr) * HD + 32 + lk * 8);
  const int sw = (lr & 7) << 4;
  const int a0 = (lk * 16) ^ sw;
  const float sc = 0.125f;

  MASK_PREPASS()

  f32x4 acc[4];
  f32x4 cacc[4] = {};
  float tsum = 0.f;

  // ---- phase 1: lsum + unnormalized PV (LDS-staged K+V, no global stores) ----
  {
    int cur = 0, stg = 2;
    STG_K(0, ldsK)
    STG_V(0, ldsV)
    STG_K(1, ldsK + 8192)
    STG_V(1, ldsV + 8192)
    for (int t = 0; t < 32; ++t) {
      BAR();
      if (t < 30) {
        STG_K(t + 2, ldsK + stg * 8192)
        STG_V(t + 2, ldsV + stg * 8192)
      }
      if (t < 30) { VMCNT(4); }
      else if (t == 30) { VMCNT(2); }
      else { VMCNT(0); }
      BAR();
      const char* Kp = ldsK + cur * 8192;
      const char* Vp = ldsV + cur * 8192;
      QKT4(Kp)
      if (maskbits & (1u << t)) { MASKADJ4(t) }
      unsigned pk0[4], pk1[4];
#pragma unroll
      for (int st = 0; st < 4; ++st) {
        float p0 = __expf(acc[st][0] * sc);
        float p1 = __expf(acc[st][1] * sc);
        float p2 = __expf(acc[st][2] * sc);
        float p3 = __expf(acc[st][3] * sc);
        tsum += p0 + p1 + p2 + p3;
        pk0[st] = pack2bf(p0, p1);
        pk1[st] = pack2bf(p2, p3);
      }
      char* Pw = lds + 49152 + (w * 2 + (t & 1)) * 2048;
#pragma unroll
      for (int st = 0; st < 4; ++st) {
        u32x2 pv;
        pv.x = pk0[st];
        pv.y = pk1[st];
        *(u32x2*)(Pw + lr * 128 + ((st * 32 + lk * 8) ^ sw)) = pv;
      }
      asm volatile("s_waitcnt lgkmcnt(0)" ::: "memory");
      __builtin_amdgcn_sched_barrier(0);
#pragma unroll
      for (int c = 0; c < 2; ++c) {
        bf16x8 af = *(const bf16x8*)(Pw + lr * 128 + ((c * 64 + lk * 16) ^ sw));
        const int voff = (c * 64 + lk * 16) ^ sw;
#pragma unroll
        for (int dt = 0; dt < 4; ++dt) {
          bf16x8 vb = *(const bf16x8*)(Vp + (dt * 16 + lr) * 128 + voff);
          cacc[dt] = __builtin_amdgcn_mfma_f32_16x16x32_bf16(af, vb, cacc[dt], 0, 0, 0);
        }
      }
      cur = cur == 2 ? 0 : cur + 1;
      stg = stg == 2 ? 0 : stg + 1;
    }
  }
  tsum += __shfl_xor(tsum, 16, 64);
  tsum += __shfl_xor(tsum, 32, 64);
  const float linv = 1.0f / tsum;

  // ctx (normalize here): lane (lr,lk) holds ctx[q=q0w+lk*4+r][d=dt*16+lr]
#pragma unroll
  for (int dt = 0; dt < 4; ++dt)
#pragma unroll
    for (int r = 0; r < 4; ++r)
      ctx[(size_t)(b * S_LEN + q0w + lk * 4 + r) * DM + h * HD + dt * 16 + lr] =
          f2bf(cacc[dt][r] * linv);

  // ---- phase 2: coalesced attn store (reuse staging LDS as per-wave tiles) --
  BAR();  // all waves done reading phase-1 LDS
  char* const Pw2 = lds + w * 8192;
  const int swp = lr << 4;
  for (int tt = 0; tt < 16; ++tt) {
#pragma unroll
    for (int half = 0; half < 2; ++half) {
      const int t = tt * 2 + half;
      bf16x8 kf0[4], kf1[4];
#pragma unroll
      for (int st = 0; st < 4; ++st) {
        const unsigned short* kp = Kbh + (size_t)(t * 64 + st * 16 + lr) * HD + lk * 8;
        kf0[st] = *(const bf16x8*)kp;
        kf1[st] = *(const bf16x8*)(kp + 32);
      }
#pragma unroll
      for (int st = 0; st < 4; ++st) {
        f32x4 a = {};
        a = __builtin_amdgcn_mfma_f32_16x16x32_bf16(kf0[st], qf0, a, 0, 0, 0);
        a = __builtin_amdgcn_mfma_f32_16x16x32_bf16(kf1[st], qf1, a, 0, 0, 0);
        acc[st] = a;
      }
      if (maskbits & (1u << t)) { MASKADJ4(t) }
      // P tile write: lane (lr,lk) holds row lr, bytes half*256+st*64+lk*16
#pragma unroll
      for (int st = 0; st < 4; ++st) {
        f32x4 p;
        p.x = __expf(acc[st][0] * sc) * linv;
        p.y = __expf(acc[st][1] * sc) * linv;
        p.z = __expf(acc[st][2] * sc) * linv;
        p.w = __expf(acc[st][3] * sc) * linv;
        *(f32x4*)(Pw2 + lr * 512 + ((half * 256 + st * 64 + lk * 16) ^ swp)) = p;
      }
    }
    asm volatile("s_waitcnt lgkmcnt(0)" ::: "memory");
    __builtin_amdgcn_sched_barrier(0);
    // 8 coalesced NT stores: inst s covers rows {2s, 2s+1} x 512B contiguous.
#pragma unroll
    for (int s = 0; s < 8; ++s) {
      const int row = s * 2 + (l >> 5);
      const int ch = (l & 31) * 16;
      f32x4 v = *(const f32x4*)(Pw2 + row * 512 + (ch ^ (row << 4)));
      __builtin_nontemporal_store(v, (f32x4*)(abase + (size_t)row * 8192 + tt * 512 + ch));
    }
  }
}

// residual + LayerNorm: out = LN(pre + Qin) * gamma + beta, rows of 1024
__global__ __launch_bounds__(256) void ln_kernel(const float* __restrict__ pre,
                                                 const float* __restrict__ Qin,
                                                 const float* __restrict__ gamma,
                                                 const float* __restrict__ beta,
                                                 float* __restrict__ out) {
  __shared__ float red[4];
  const int row = blockIdx.x;
  const int tid = threadIdx.x;
  const int wv = tid >> 6, l = tid & 63;
  const float4 a = reinterpret_cast<const float4*>(pre + (size_t)row * DM)[tid];
  const float4 q = reinterpret_cast<const float4*>(Qin + (size_t)row * DM)[tid];
  float x0 = a.x + q.x, x1 = a.y + q.y, x2 = a.z + q.z, x3 = a.w + q.w;
  float s = x0 + x1 + x2 + x3;
#pragma unroll
  for (int off = 32; off >= 1; off >>= 1) s += __shfl_xor(s, off, 64);
  if (l == 0) red[wv] = s;
  __syncthreads();
  float mean = (red[0] + red[1] + red[2] + red[3]) * (1.0f / 1024.0f);
  __syncthreads();
  float d0 = x0 - mean, d1 = x1 - mean, d2 = x2 - mean, d3 = x3 - mean;
  float s2 = d0 * d0 + d1 * d1 + d2 * d2 + d3 * d3;
#pragma unroll
  for (int off = 32; off >= 1; off >>= 1) s2 += __shfl_xor(s2, off, 64);
  if (l == 0) red[wv] = s2;
  __syncthreads();
  float var = (red[0] + red[1] + red[2] + red[3]) * (1.0f / 1024.0f);
  float rstd = rsqrtf(var + 1e-5f);
  const float4 g = reinterpret_cast<const float4*>(gamma)[tid];
  const float4 bt = reinterpret_cast<const float4*>(beta)[tid];
  float4 o;
  o.x = d0 * rstd * g.x + bt.x;
  o.y = d1 * rstd * g.y + bt.y;
  o.z = d2 * rstd * g.z + bt.z;
  o.w = d3 * rstd * g.w + bt.w;
  reinterpret_cast<float4*>(out + (size_t)row * DM)[tid] = o;
}

extern "C" void kernel_launch(void* const* d_in, const int* in_sizes, int n_in,
                              void* d_out, int out_size, void* d_ws, size_t ws_size,
                              hipStream_t stream) {
  const float* Qi = (const float*)d_in[0];
  const float* Ki = (const float*)d_in[1];
  const float* Vi = (const float*)d_in[2];
  const unsigned char* mask = (const unsigned char*)d_in[3];
  const float* Wq = (const float*)d_in[4];
  const float* bq = (const float*)d_in[5];
  const float* Wk = (const float*)d_in[6];
  const float* bk = (const float*)d_in[7];
  const float* Wv = (const float*)d_in[8];
  const float* bv = (const float*)d_in[9];
  const float* Wo = (const float*)d_in[10];
  const float* bo = (const float*)d_in[11];
  const float* gamma = (const float*)d_in[12];
  const float* beta = (const float*)d_in[13];

  char* ws = (char*)d_ws;
  unsigned short* Qb = (unsigned short*)(ws);            // [4096][1024] bf16
  unsigned short* Kb = Qb + 4194304;
  unsigned short* Vb = Qb + 2 * 4194304;
  unsigned short* Wtq = (unsigned short*)(ws + 25165824);  // [n][k] bf16 x4
  unsigned short* Wtk = Wtq + 1048576;
  unsigned short* Wtv = Wtq + 2 * 1048576;
  unsigned short* Wto = Wtq + 3 * 1048576;
  unsigned short* Qhd = (unsigned short*)(ws + 33554432);  // [B,H,S,64] bf16
  unsigned short* Khd = (unsigned short*)(ws + 41943040);  // [B,H,S,64] bf16
  unsigned short* Vtd = (unsigned short*)(ws + 50331648);  // [B,H,64,S] bf16
  unsigned short* ctx = (unsigned short*)(ws);             // reuse Qb region
  float* preLN = (float*)(ws + 8388608);                   // reuse Kb/Vb region

  float* out0 = (float*)d_out;
  float* attn = out0 + 4194304;

  prep_kernel<<<16384, 256, 0, stream>>>(Qi, Ki, Vi, Qb, Kb, Vb,
                                         Wq, Wk, Wv, Wo, Wtq, Wtk, Wtv, Wto);
  dim3 gqkv(32, 8, 3);
  gemm_qkv<<<gqkv, 256, 0, stream>>>(Qb, Kb, Vb, Wtq, Wtk, Wtv,
                                     bq, bk, bv, Qhd, Khd, Vtd);
  attn_fused_kernel<<<512, 512, 0, stream>>>(Qhd, Khd, Vtd, mask, attn, ctx);
  dim3 gg(32, 16);
  gemm_out<<<gg, 256, 0, stream>>>(ctx, Wto, bo, preLN);
  ln_kernel<<<4096, 256, 0, stream>>>(preLN, Qi, gamma, beta, out0);
}

// Round 20
// 298.555 us; speedup vs baseline: 1.6306x; 1.0051x over previous
//
#include <hip/hip_runtime.h>
#include <hip/hip_bf16.h>

#define S_LEN 2048
#define NH 16
#define HD 64
#define DM 1024

typedef float f32x4 __attribute__((ext_vector_type(4)));
typedef unsigned u32x4 __attribute__((ext_vector_type(4)));
typedef unsigned u32x2 __attribute__((ext_vector_type(2)));
typedef __bf16 bf16x8 __attribute__((ext_vector_type(8)));

#define BAR() __builtin_amdgcn_s_barrier()
#define VMCNT(N) asm volatile("s_waitcnt vmcnt(" #N ")" ::: "memory")

__device__ __forceinline__ unsigned short f2bf(float f) {
  union { float f; unsigned u; } v; v.f = f;
  unsigned r = v.u + 0x7fffu + ((v.u >> 16) & 1u);
  return (unsigned short)(r >> 16);
}

__device__ __forceinline__ unsigned pack2bf(float lo, float hi) {
  return (unsigned)f2bf(lo) | ((unsigned)f2bf(hi) << 16);
}

__device__ __forceinline__ void load_lds16(const void* g, void* l) {
  __builtin_amdgcn_global_load_lds((const __attribute__((address_space(1))) void*)g,
                                   (__attribute__((address_space(3))) void*)l, 16, 0, 0);
}

// Fused prep: blocks [0,12288) convert Q/K/V fp32->bf16; blocks [12288,16384)
// transpose+convert the 4 weight matrices (32x32 tiles).
__global__ __launch_bounds__(256) void prep_kernel(const float* __restrict__ Qi,
                                                   const float* __restrict__ Ki,
                                                   const float* __restrict__ Vi,
                                                   unsigned short* __restrict__ Qb,
                                                   unsigned short* __restrict__ Kb,
                                                   unsigned short* __restrict__ Vb,
                                                   const float* __restrict__ Wq,
                                                   const float* __restrict__ Wk,
                                                   const float* __restrict__ Wv,
                                                   const float* __restrict__ Wo,
                                                   unsigned short* __restrict__ Wtq,
                                                   unsigned short* __restrict__ Wtk,
                                                   unsigned short* __restrict__ Wtv,
                                                   unsigned short* __restrict__ Wto) {
  __shared__ float t[32][33];
  const int bid = blockIdx.x;
  if (bid < 12288) {
    int sel = bid >> 12;
    int i = (bid & 4095) * 256 + threadIdx.x;
    const float* in = sel == 0 ? Qi : (sel == 1 ? Ki : Vi);
    unsigned short* out = sel == 0 ? Qb : (sel == 1 ? Kb : Vb);
    float4 v = reinterpret_cast<const float4*>(in)[i];
    ushort4 o;
    o.x = f2bf(v.x); o.y = f2bf(v.y); o.z = f2bf(v.z); o.w = f2bf(v.w);
    reinterpret_cast<ushort4*>(out)[i] = o;
  } else {
    int r = bid - 12288;
    int wi = r >> 10, ti = r & 1023;
    const float* W = wi == 0 ? Wq : (wi == 1 ? Wk : (wi == 2 ? Wv : Wo));
    unsigned short* Wt = wi == 0 ? Wtq : (wi == 1 ? Wtk : (wi == 2 ? Wtv : Wto));
    int bx = (ti & 31) * 32;  // n base
    int by = (ti >> 5) * 32;  // k base
    int tx = threadIdx.x & 31, ty = threadIdx.x >> 5;
    for (int i = ty; i < 32; i += 8) t[i][tx] = W[(size_t)(by + i) * DM + bx + tx];
    __syncthreads();
    for (int i = ty; i < 32; i += 8) Wt[(size_t)(bx + i) * DM + by + tx] = f2bf(t[tx][i]);
  }
}

// All three projection GEMMs in one launch: grid (32,8,3), 128x128 tile.
__global__ __launch_bounds__(256) void gemm_qkv(const unsigned short* __restrict__ Qb,
                                                const unsigned short* __restrict__ Kb,
                                                const unsigned short* __restrict__ Vb,
                                                const unsigned short* __restrict__ Wtq,
                                                const unsigned short* __restrict__ Wtk,
                                                const unsigned short* __restrict__ Wtv,
                                                const float* __restrict__ bq,
                                                const float* __restrict__ bk,
                                                const float* __restrict__ bv,
                                                unsigned short* __restrict__ Qhd,
                                                unsigned short* __restrict__ Khd,
                                                unsigned short* __restrict__ Vtd) {
  constexpr int K = 1024;
  __shared__ unsigned short Al[128 * 32];
  __shared__ unsigned short Bl[128 * 32];
  const int z = blockIdx.z;
  const unsigned short* A = z == 0 ? Qb : (z == 1 ? Kb : Vb);
  const unsigned short* Bt = z == 0 ? Wtq : (z == 1 ? Wtk : Wtv);
  const float* bias = z == 0 ? bq : (z == 1 ? bk : bv);
  unsigned short* C = z == 0 ? Qhd : (z == 1 ? Khd : Vtd);
  const int tid = threadIdx.x;
  const int w = tid >> 6, l = tid & 63;
  const int m0 = blockIdx.x * 128, n0 = blockIdx.y * 128;
  const int wr = (w >> 1) * 64, wc = (w & 1) * 64;
  const int lr = l & 15, lk = l >> 4;
  f32x4 acc[4][4] = {};
  for (int kt = 0; kt < K; kt += 32) {
#pragma unroll
    for (int i = 0; i < 2; ++i) {
      int seg = i * 256 + tid;
      int row = seg >> 2, ks = (seg & 3) * 8;
      load_lds16(A + (size_t)(m0 + row) * K + kt + ks, Al + seg * 8);
      load_lds16(Bt + (size_t)(n0 + row) * K + kt + ks, Bl + seg * 8);
    }
    __syncthreads();
    bf16x8 af[4], bfr[4];
#pragma unroll
    for (int t = 0; t < 4; ++t) af[t] = *(const bf16x8*)(Al + (wr + t * 16 + lr) * 32 + lk * 8);
#pragma unroll
    for (int t = 0; t < 4; ++t) bfr[t] = *(const bf16x8*)(Bl + (wc + t * 16 + lr) * 32 + lk * 8);
#pragma unroll
    for (int i = 0; i < 4; ++i)
#pragma unroll
      for (int j = 0; j < 4; ++j)
        acc[i][j] = __builtin_amdgcn_mfma_f32_16x16x32_bf16(af[i], bfr[j], acc[i][j], 0, 0, 0);
    __syncthreads();
  }
  const int drow = lk * 4, dcol = lr;
  if (z < 2) {
#pragma unroll
    for (int i = 0; i < 4; ++i)
#pragma unroll
      for (int j = 0; j < 4; ++j) {
        int n = n0 + wc + j * 16 + dcol;
        float bv_ = bias[n];
        int h = n >> 6, d = n & 63;
#pragma unroll
        for (int r = 0; r < 4; ++r) {
          int m = m0 + wr + i * 16 + drow + r;
          int b = m >> 11, s = m & 2047;
          C[((size_t)(b * NH + h) * S_LEN + s) * HD + d] = f2bf(acc[i][j][r] + bv_);
        }
      }
  } else {
#pragma unroll
    for (int i = 0; i < 4; ++i) {
      int m = m0 + wr + i * 16 + drow;
      int b = m >> 11, s = m & 2047;
#pragma unroll
      for (int j = 0; j < 4; ++j) {
        int n = n0 + wc + j * 16 + dcol;
        float bv_ = bias[n];
        int h = n >> 6, d = n & 63;
        ushort4 o;
        o.x = f2bf(acc[i][j][0] + bv_);
        o.y = f2bf(acc[i][j][1] + bv_);
        o.z = f2bf(acc[i][j][2] + bv_);
        o.w = f2bf(acc[i][j][3] + bv_);
        *reinterpret_cast<ushort4*>(C + ((size_t)(b * NH + h) * HD + d) * S_LEN + s) = o;
      }
    }
  }
}

// Output projection GEMM (fp32 rowmajor out), 128x64 tile, grid (32,16).
__global__ __launch_bounds__(256) void gemm_out(const unsigned short* __restrict__ A,
                                                const unsigned short* __restrict__ Bt,
                                                const float* __restrict__ bias,
                                                float* __restrict__ C) {
  constexpr int K = 1024;
  constexpr int N = 1024;
  __shared__ unsigned short Al[128 * 32];
  __shared__ unsigned short Bl[64 * 32];
  const int tid = threadIdx.x;
  const int w = tid >> 6, l = tid & 63;
  const int m0 = blockIdx.x * 128, n0 = blockIdx.y * 64;
  const int wr = (w >> 1) * 64, wc = (w & 1) * 32;
  const int lr = l & 15, lk = l >> 4;
  f32x4 acc[4][2] = {};
  for (int kt = 0; kt < K; kt += 32) {
#pragma unroll
    for (int i = 0; i < 2; ++i) {
      int seg = i * 256 + tid;
      int row = seg >> 2, ks = (seg & 3) * 8;
      load_lds16(A + (size_t)(m0 + row) * K + kt + ks, Al + seg * 8);
    }
    {
      int row = tid >> 2, ks = (tid & 3) * 8;
      load_lds16(Bt + (size_t)(n0 + row) * K + kt + ks, Bl + tid * 8);
    }
    __syncthreads();
    bf16x8 af[4], bfr[2];
#pragma unroll
    for (int t = 0; t < 4; ++t) af[t] = *(const bf16x8*)(Al + (wr + t * 16 + lr) * 32 + lk * 8);
#pragma unroll
    for (int t = 0; t < 2; ++t) bfr[t] = *(const bf16x8*)(Bl + (wc + t * 16 + lr) * 32 + lk * 8);
#pragma unroll
    for (int i = 0; i < 4; ++i)
#pragma unroll
      for (int j = 0; j < 2; ++j)
        acc[i][j] = __builtin_amdgcn_mfma_f32_16x16x32_bf16(af[i], bfr[j], acc[i][j], 0, 0, 0);
    __syncthreads();
  }
  const int drow = lk * 4, dcol = lr;
#pragma unroll
  for (int i = 0; i < 4; ++i)
#pragma unroll
    for (int j = 0; j < 2; ++j) {
      int n = n0 + wc + j * 16 + dcol;
      float bv = bias[n];
#pragma unroll
      for (int r = 0; r < 4; ++r) {
        int m = m0 + wr + i * 16 + drow + r;
        C[(size_t)m * N + n] = acc[i][j][r] + bv;
      }
    }
}

// ---------------------------------------------------------------------------
// Fused attention, KVBLK=128 2-buffer variant of the verified R16 structure:
//  phase 1: K+V LDS-staged (2 buffers of 16KB each, depth-1 prefetch, counted
//           VMCNT(4)); per 128-k tile, two 64-k half-bodies identical to the
//           verified R16 body. 32 block barriers (was 64). P-remap is a SINGLE
//           per-wave 2KB buffer (8x2KB = 16KB at 65536, fits exactly; safe:
//           per-wave DS ops execute in order and each half is write->fence->
//           read, the same pattern phase 2 has used since R14).
//  phase 2: register-direct K, p=exp(s)*linv, coalesced attn store (unchanged).
// R17 lesson: with the per-iteration lgkmcnt(0)+sched_barrier(0) fence, K/V
// must be staged via global_load_lds.
// Swapped QK^T (A=K,B=Q): lane (lr,lk) holds S[k=t*64+st*16+lk*4+r][q=q0w+lr].
// ---------------------------------------------------------------------------
#define STG_K128(T, BASE)                                                      \
  _Pragma("unroll") for (int i_ = 0; i_ < 2; ++i_) {                           \
    int s_ = i_ * 512 + tid;                                                   \
    int row_ = s_ >> 3, cb_ = (s_ & 7) * 16;                                   \
    load_lds16((const char*)Kbh + (size_t)((T) * 128 + row_) * 128 +           \
                   (cb_ ^ ((row_ & 7) << 4)),                                  \
               (BASE) + s_ * 16);                                              \
  }

#define STG_V128(T, BASE)                                                      \
  _Pragma("unroll") for (int i_ = 0; i_ < 2; ++i_) {                           \
    int s_ = i_ * 512 + tid;                                                   \
    int row_ = s_ >> 4, cb_ = (s_ & 15) * 16;                                  \
    load_lds16((const char*)Vbh + (size_t)row_ * 4096 + (T) * 256 +            \
                   (cb_ ^ ((row_ & 7) << 4)),                                  \
               (BASE) + s_ * 16);                                              \
  }

#define QKT4H(KPTR)                                                            \
  _Pragma("unroll") for (int st = 0; st < 4; ++st) {                           \
    const char* rp = (KPTR) + (st * 16 + lr) * 128;                            \
    bf16x8 k0 = *(const bf16x8*)(rp + a0);                                     \
    bf16x8 k1 = *(const bf16x8*)(rp + (a0 ^ 64));                              \
    f32x4 a = {};                                                              \
    a = __builtin_amdgcn_mfma_f32_16x16x32_bf16(k0, qf0, a, 0, 0, 0);          \
    a = __builtin_amdgcn_mfma_f32_16x16x32_bf16(k1, qf1, a, 0, 0, 0);          \
    acc[st] = a;                                                               \
  }

#define MASKADJ4(T)                                                            \
  _Pragma("unroll") for (int st = 0; st < 4; ++st) {                           \
    uchar4 m4 = *(const uchar4*)(mrow + (T) * 64 + st * 16 + lk * 4);          \
    if (m4.x) acc[st][0] = -8e9f;                                              \
    if (m4.y) acc[st][1] = -8e9f;                                              \
    if (m4.z) acc[st][2] = -8e9f;                                              \
    if (m4.w) acc[st][3] = -8e9f;                                              \
  }

#define MASK_PREPASS()                                                         \
  unsigned maskbits = 0;                                                       \
  _Pragma("unroll") for (int g4 = 0; g4 < 4; ++g4) {                           \
    unsigned mm[8];                                                            \
    const char* mp = (const char*)mrow + g4 * 512 + lk * 16;                   \
    _Pragma("unroll") for (int q8 = 0; q8 < 8; ++q8) {                         \
      u32x4 v = __builtin_nontemporal_load((const u32x4*)(mp + q8 * 64));      \
      mm[q8] = v.x | v.y | v.z | v.w;                                          \
    }                                                                          \
    _Pragma("unroll") for (int q8 = 0; q8 < 8; ++q8)                           \
      if (__any(mm[q8] != 0)) maskbits |= 1u << (g4 * 8 + q8);                 \
  }

__global__ __launch_bounds__(512, 4) void attn_fused_kernel(const unsigned short* __restrict__ Qh,
                                                            const unsigned short* __restrict__ Kh,
                                                            const unsigned short* __restrict__ Vt,
                                                            const unsigned char* __restrict__ mask,
                                                            float* __restrict__ attn_out,
                                                            unsigned short* __restrict__ ctx) {
  __shared__ char lds[81920];  // ph1: K 2x16KB @0, V 2x16KB @32768, Premap 8x2KB @65536
                               // ph2: per-wave 8KB P-store tiles @0 (64KB)
  char* const ldsK = lds;
  char* const ldsV = lds + 32768;
  const int tid = threadIdx.x;
  const int w = tid >> 6, l = tid & 63;
  const int lr = l & 15, lk = l >> 4;
  const int L = blockIdx.x;
  const int g = L & 7, j = L >> 3;
  const int bh = g * 4 + (j & 3);
  const int qt = j >> 2;
  const int q0w = qt * 128 + w * 16;
  const int b = bh >> 4, h = bh & 15;
  const unsigned short* Qbh = Qh + (size_t)bh * S_LEN * HD;
  const unsigned short* Kbh = Kh + (size_t)bh * S_LEN * HD;
  const unsigned short* Vbh = Vt + (size_t)bh * HD * S_LEN;
  const unsigned char* mrow = mask + (size_t)b * S_LEN * S_LEN + (size_t)(q0w + lr) * S_LEN;
  char* const abase = (char*)(attn_out + ((size_t)bh * S_LEN + q0w) * S_LEN);

  bf16x8 qf0 = *(const bf16x8*)(Qbh + (q0w + lr) * HD + lk * 8);
  bf16x8 qf1 = *(const bf16x8*)(Qbh + (q0w + lr) * HD + 32 + lk * 8);
  const int sw = (lr & 7) << 4;
  const int a0 = (lk * 16) ^ sw;
  const float sc = 0.125f;

  MASK_PREPASS()

  f32x4 acc[4];
  f32x4 cacc[4] = {};
  float tsum = 0.f;

  // ---- phase 1: lsum + unnormalized PV (KVBLK=128, 2-buffer staging) ----
  {
    STG_K128(0, ldsK)
    STG_V128(0, ldsV)
    char* const Pw = lds + 65536 + w * 2048;  // single per-wave buffer (16KB total)
    for (int T = 0; T < 16; ++T) {
      const int buf = T & 1;
      BAR();
      if (T < 15) {
        STG_K128(T + 1, ldsK + (buf ^ 1) * 16384)
        STG_V128(T + 1, ldsV + (buf ^ 1) * 16384)
      }
      if (T < 15) { VMCNT(4); } else { VMCNT(0); }
      BAR();
#pragma unroll
      for (int half = 0; half < 2; ++half) {
        const int t = 2 * T + half;
        const char* Kp = ldsK + buf * 16384 + half * 8192;
        const char* Vp = ldsV + buf * 16384;
        QKT4H(Kp)
        if (maskbits & (1u << t)) { MASKADJ4(t) }
        unsigned pk0[4], pk1[4];
#pragma unroll
        for (int st = 0; st < 4; ++st) {
          float p0 = __expf(acc[st][0] * sc);
          float p1 = __expf(acc[st][1] * sc);
          float p2 = __expf(acc[st][2] * sc);
          float p3 = __expf(acc[st][3] * sc);
          tsum += p0 + p1 + p2 + p3;
          pk0[st] = pack2bf(p0, p1);
          pk1[st] = pack2bf(p2, p3);
        }
#pragma unroll
        for (int st = 0; st < 4; ++st) {
          u32x2 pv;
          pv.x = pk0[st];
          pv.y = pk1[st];
          *(u32x2*)(Pw + lr * 128 + ((st * 32 + lk * 8) ^ sw)) = pv;
        }
        asm volatile("s_waitcnt lgkmcnt(0)" ::: "memory");
        __builtin_amdgcn_sched_barrier(0);
#pragma unroll
        for (int c = 0; c < 2; ++c) {
          bf16x8 af = *(const bf16x8*)(Pw + lr * 128 + ((c * 64 + lk * 16) ^ sw));
          const int voff = (half * 128 + c * 64 + lk * 16) ^ sw;
#pragma unroll
          for (int dt = 0; dt < 4; ++dt) {
            bf16x8 vb = *(const bf16x8*)(Vp + (dt * 16 + lr) * 256 + voff);
            cacc[dt] = __builtin_amdgcn_mfma_f32_16x16x32_bf16(af, vb, cacc[dt], 0, 0, 0);
          }
        }
      }
    }
  }
  tsum += __shfl_xor(tsum, 16, 64);
  tsum += __shfl_xor(tsum, 32, 64);
  const float linv = 1.0f / tsum;

  // ctx (normalize here): lane (lr,lk) holds ctx[q=q0w+lk*4+r][d=dt*16+lr]
#pragma unroll
  for (int dt = 0; dt < 4; ++dt)
#pragma unroll
    for (int r = 0; r < 4; ++r)
      ctx[(size_t)(b * S_LEN + q0w + lk * 4 + r) * DM + h * HD + dt * 16 + lr] =
          f2bf(cacc[dt][r] * linv);

  // ---- phase 2: coalesced attn store (reuse staging LDS as per-wave tiles) --
  BAR();  // all waves done reading phase-1 LDS
  char* const Pw2 = lds + w * 8192;
  const int swp = lr << 4;
  for (int tt = 0; tt < 16; ++tt) {
#pragma unroll
    for (int half = 0; half < 2; ++half) {
      const int t = tt * 2 + half;
      bf16x8 kf0[4], kf1[4];
#pragma unroll
      for (int st = 0; st < 4; ++st) {
        const unsigned short* kp = Kbh + (size_t)(t * 64 + st * 16 + lr) * HD + lk * 8;
        kf0[st] = *(const bf16x8*)kp;
        kf1[st] = *(const bf16x8*)(kp + 32);
      }
#pragma unroll
      for (int st = 0; st < 4; ++st) {
        f32x4 a = {};
        a = __builtin_amdgcn_mfma_f32_16x16x32_bf16(kf0[st], qf0, a, 0, 0, 0);
        a = __builtin_amdgcn_mfma_f32_16x16x32_bf16(kf1[st], qf1, a, 0, 0, 0);
        acc[st] = a;
      }
      if (maskbits & (1u << t)) { MASKADJ4(t) }
      // P tile write: lane (lr,lk) holds row lr, bytes half*256+st*64+lk*16
#pragma unroll
      for (int st = 0; st < 4; ++st) {
        f32x4 p;
        p.x = __expf(acc[st][0] * sc) * linv;
        p.y = __expf(acc[st][1] * sc) * linv;
        p.z = __expf(acc[st][2] * sc) * linv;
        p.w = __expf(acc[st][3] * sc) * linv;
        *(f32x4*)(Pw2 + lr * 512 + ((half * 256 + st * 64 + lk * 16) ^ swp)) = p;
      }
    }
    asm volatile("s_waitcnt lgkmcnt(0)" ::: "memory");
    __builtin_amdgcn_sched_barrier(0);
    // 8 coalesced NT stores: inst s covers rows {2s, 2s+1} x 512B contiguous.
#pragma unroll
    for (int s = 0; s < 8; ++s) {
      const int row = s * 2 + (l >> 5);
      const int ch = (l & 31) * 16;
      f32x4 v = *(const f32x4*)(Pw2 + row * 512 + (ch ^ (row << 4)));
      __builtin_nontemporal_store(v, (f32x4*)(abase + (size_t)row * 8192 + tt * 512 + ch));
    }
  }
}

// residual + LayerNorm: out = LN(pre + Qin) * gamma + beta, rows of 1024
__global__ __launch_bounds__(256) void ln_kernel(const float* __restrict__ pre,
                                                 const float* __restrict__ Qin,
                                                 const float* __restrict__ gamma,
                                                 const float* __restrict__ beta,
                                                 float* __restrict__ out) {
  __shared__ float red[4];
  const int row = blockIdx.x;
  const int tid = threadIdx.x;
  const int wv = tid >> 6, l = tid & 63;
  const float4 a = reinterpret_cast<const float4*>(pre + (size_t)row * DM)[tid];
  const float4 q = reinterpret_cast<const float4*>(Qin + (size_t)row * DM)[tid];
  float x0 = a.x + q.x, x1 = a.y + q.y, x2 = a.z + q.z, x3 = a.w + q.w;
  float s = x0 + x1 + x2 + x3;
#pragma unroll
  for (int off = 32; off >= 1; off >>= 1) s += __shfl_xor(s, off, 64);
  if (l == 0) red[wv] = s;
  __syncthreads();
  float mean = (red[0] + red[1] + red[2] + red[3]) * (1.0f / 1024.0f);
  __syncthreads();
  float d0 = x0 - mean, d1 = x1 - mean, d2 = x2 - mean, d3 = x3 - mean;
  float s2 = d0 * d0 + d1 * d1 + d2 * d2 + d3 * d3;
#pragma unroll
  for (int off = 32; off >= 1; off >>= 1) s2 += __shfl_xor(s2, off, 64);
  if (l == 0) red[wv] = s2;
  __syncthreads();
  float var = (red[0] + red[1] + red[2] + red[3]) * (1.0f / 1024.0f);
  float rstd = rsqrtf(var + 1e-5f);
  const float4 g = reinterpret_cast<const float4*>(gamma)[tid];
  const float4 bt = reinterpret_cast<const float4*>(beta)[tid];
  float4 o;
  o.x = d0 * rstd * g.x + bt.x;
  o.y = d1 * rstd * g.y + bt.y;
  o.z = d2 * rstd * g.z + bt.z;
  o.w = d3 * rstd * g.w + bt.w;
  reinterpret_cast<float4*>(out + (size_t)row * DM)[tid] = o;
}

extern "C" void kernel_launch(void* const* d_in, const int* in_sizes, int n_in,
                              void* d_out, int out_size, void* d_ws, size_t ws_size,
                              hipStream_t stream) {
  const float* Qi = (const float*)d_in[0];
  const float* Ki = (const float*)d_in[1];
  const float* Vi = (const float*)d_in[2];
  const unsigned char* mask = (const unsigned char*)d_in[3];
  const float* Wq = (const float*)d_in[4];
  const float* bq = (const float*)d_in[5];
  const float* Wk = (const float*)d_in[6];
  const float* bk = (const float*)d_in[7];
  const float* Wv = (const float*)d_in[8];
  const float* bv = (const float*)d_in[9];
  const float* Wo = (const float*)d_in[10];
  const float* bo = (const float*)d_in[11];
  const float* gamma = (const float*)d_in[12];
  const float* beta = (const float*)d_in[13];

  char* ws = (char*)d_ws;
  unsigned short* Qb = (unsigned short*)(ws);            // [4096][1024] bf16
  unsigned short* Kb = Qb + 4194304;
  unsigned short* Vb = Qb + 2 * 4194304;
  unsigned short* Wtq = (unsigned short*)(ws + 25165824);  // [n][k] bf16 x4
  unsigned short* Wtk = Wtq + 1048576;
  unsigned short* Wtv = Wtq + 2 * 1048576;
  unsigned short* Wto = Wtq + 3 * 1048576;
  unsigned short* Qhd = (unsigned short*)(ws + 33554432);  // [B,H,S,64] bf16
  unsigned short* Khd = (unsigned short*)(ws + 41943040);  // [B,H,S,64] bf16
  unsigned short* Vtd = (unsigned short*)(ws + 50331648);  // [B,H,64,S] bf16
  unsigned short* ctx = (unsigned short*)(ws);             // reuse Qb region
  float* preLN = (float*)(ws + 8388608);                   // reuse Kb/Vb region

  float* out0 = (float*)d_out;
  float* attn = out0 + 4194304;

  prep_kernel<<<16384, 256, 0, stream>>>(Qi, Ki, Vi, Qb, Kb, Vb,
                                         Wq, Wk, Wv, Wo, Wtq, Wtk, Wtv, Wto);
  dim3 gqkv(32, 8, 3);
  gemm_qkv<<<gqkv, 256, 0, stream>>>(Qb, Kb, Vb, Wtq, Wtk, Wtv,
                                     bq, bk, bv, Qhd, Khd, Vtd);
  attn_fused_kernel<<<512, 512, 0, stream>>>(Qhd, Khd, Vtd, mask, attn, ctx);
  dim3 gg(32, 16);
  gemm_out<<<gg, 256, 0, stream>>>(ctx, Wto, bo, preLN);
  ln_kernel<<<4096, 256, 0, stream>>>(preLN, Qi, gamma, beta, out0);
}

// Round 21
// 295.890 us; speedup vs baseline: 1.6452x; 1.0090x over previous
//
#include <hip/hip_runtime.h>
#include <hip/hip_bf16.h>

#define S_LEN 2048
#define NH 16
#define HD 64
#define DM 1024

typedef float f32x4 __attribute__((ext_vector_type(4)));
typedef unsigned u32x4 __attribute__((ext_vector_type(4)));
typedef unsigned u32x2 __attribute__((ext_vector_type(2)));
typedef __bf16 bf16x8 __attribute__((ext_vector_type(8)));

#define BAR() __builtin_amdgcn_s_barrier()
#define VMCNT(N) asm volatile("s_waitcnt vmcnt(" #N ")" ::: "memory")

__device__ __forceinline__ unsigned short f2bf(float f) {
  union { float f; unsigned u; } v; v.f = f;
  unsigned r = v.u + 0x7fffu + ((v.u >> 16) & 1u);
  return (unsigned short)(r >> 16);
}

__device__ __forceinline__ unsigned pack2bf(float lo, float hi) {
  return (unsigned)f2bf(lo) | ((unsigned)f2bf(hi) << 16);
}

__device__ __forceinline__ void load_lds16(const void* g, void* l) {
  __builtin_amdgcn_global_load_lds((const __attribute__((address_space(1))) void*)g,
                                   (__attribute__((address_space(3))) void*)l, 16, 0, 0);
}

// Fused prep: blocks [0,12288) convert Q/K/V fp32->bf16; blocks [12288,16384)
// transpose+convert the 4 weight matrices (32x32 tiles).
__global__ __launch_bounds__(256) void prep_kernel(const float* __restrict__ Qi,
                                                   const float* __restrict__ Ki,
                                                   const float* __restrict__ Vi,
                                                   unsigned short* __restrict__ Qb,
                                                   unsigned short* __restrict__ Kb,
                                                   unsigned short* __restrict__ Vb,
                                                   const float* __restrict__ Wq,
                                                   const float* __restrict__ Wk,
                                                   const float* __restrict__ Wv,
                                                   const float* __restrict__ Wo,
                                                   unsigned short* __restrict__ Wtq,
                                                   unsigned short* __restrict__ Wtk,
                                                   unsigned short* __restrict__ Wtv,
                                                   unsigned short* __restrict__ Wto) {
  __shared__ float t[32][33];
  const int bid = blockIdx.x;
  if (bid < 12288) {
    int sel = bid >> 12;
    int i = (bid & 4095) * 256 + threadIdx.x;
    const float* in = sel == 0 ? Qi : (sel == 1 ? Ki : Vi);
    unsigned short* out = sel == 0 ? Qb : (sel == 1 ? Kb : Vb);
    float4 v = reinterpret_cast<const float4*>(in)[i];
    ushort4 o;
    o.x = f2bf(v.x); o.y = f2bf(v.y); o.z = f2bf(v.z); o.w = f2bf(v.w);
    reinterpret_cast<ushort4*>(out)[i] = o;
  } else {
    int r = bid - 12288;
    int wi = r >> 10, ti = r & 1023;
    const float* W = wi == 0 ? Wq : (wi == 1 ? Wk : (wi == 2 ? Wv : Wo));
    unsigned short* Wt = wi == 0 ? Wtq : (wi == 1 ? Wtk : (wi == 2 ? Wtv : Wto));
    int bx = (ti & 31) * 32;  // n base
    int by = (ti >> 5) * 32;  // k base
    int tx = threadIdx.x & 31, ty = threadIdx.x >> 5;
    for (int i = ty; i < 32; i += 8) t[i][tx] = W[(size_t)(by + i) * DM + bx + tx];
    __syncthreads();
    for (int i = ty; i < 32; i += 8) Wt[(size_t)(bx + i) * DM + by + tx] = f2bf(t[tx][i]);
  }
}

// All three projection GEMMs in one launch: grid (32,8,3), 128x128 tile.
__global__ __launch_bounds__(256) void gemm_qkv(const unsigned short* __restrict__ Qb,
                                                const unsigned short* __restrict__ Kb,
                                                const unsigned short* __restrict__ Vb,
                                                const unsigned short* __restrict__ Wtq,
                                                const unsigned short* __restrict__ Wtk,
                                                const unsigned short* __restrict__ Wtv,
                                                const float* __restrict__ bq,
                                                const float* __restrict__ bk,
                                                const float* __restrict__ bv,
                                                unsigned short* __restrict__ Qhd,
                                                unsigned short* __restrict__ Khd,
                                                unsigned short* __restrict__ Vtd) {
  constexpr int K = 1024;
  __shared__ unsigned short Al[128 * 32];
  __shared__ unsigned short Bl[128 * 32];
  const int z = blockIdx.z;
  const unsigned short* A = z == 0 ? Qb : (z == 1 ? Kb : Vb);
  const unsigned short* Bt = z == 0 ? Wtq : (z == 1 ? Wtk : Wtv);
  const float* bias = z == 0 ? bq : (z == 1 ? bk : bv);
  unsigned short* C = z == 0 ? Qhd : (z == 1 ? Khd : Vtd);
  const int tid = threadIdx.x;
  const int w = tid >> 6, l = tid & 63;
  const int m0 = blockIdx.x * 128, n0 = blockIdx.y * 128;
  const int wr = (w >> 1) * 64, wc = (w & 1) * 64;
  const int lr = l & 15, lk = l >> 4;
  f32x4 acc[4][4] = {};
  for (int kt = 0; kt < K; kt += 32) {
#pragma unroll
    for (int i = 0; i < 2; ++i) {
      int seg = i * 256 + tid;
      int row = seg >> 2, ks = (seg & 3) * 8;
      load_lds16(A + (size_t)(m0 + row) * K + kt + ks, Al + seg * 8);
      load_lds16(Bt + (size_t)(n0 + row) * K + kt + ks, Bl + seg * 8);
    }
    __syncthreads();
    bf16x8 af[4], bfr[4];
#pragma unroll
    for (int t = 0; t < 4; ++t) af[t] = *(const bf16x8*)(Al + (wr + t * 16 + lr) * 32 + lk * 8);
#pragma unroll
    for (int t = 0; t < 4; ++t) bfr[t] = *(const bf16x8*)(Bl + (wc + t * 16 + lr) * 32 + lk * 8);
#pragma unroll
    for (int i = 0; i < 4; ++i)
#pragma unroll
      for (int j = 0; j < 4; ++j)
        acc[i][j] = __builtin_amdgcn_mfma_f32_16x16x32_bf16(af[i], bfr[j], acc[i][j], 0, 0, 0);
    __syncthreads();
  }
  const int drow = lk * 4, dcol = lr;
  if (z < 2) {
#pragma unroll
    for (int i = 0; i < 4; ++i)
#pragma unroll
      for (int j = 0; j < 4; ++j) {
        int n = n0 + wc + j * 16 + dcol;
        float bv_ = bias[n];
        int h = n >> 6, d = n & 63;
#pragma unroll
        for (int r = 0; r < 4; ++r) {
          int m = m0 + wr + i * 16 + drow + r;
          int b = m >> 11, s = m & 2047;
          C[((size_t)(b * NH + h) * S_LEN + s) * HD + d] = f2bf(acc[i][j][r] + bv_);
        }
      }
  } else {
#pragma unroll
    for (int i = 0; i < 4; ++i) {
      int m = m0 + wr + i * 16 + drow;
      int b = m >> 11, s = m & 2047;
#pragma unroll
      for (int j = 0; j < 4; ++j) {
        int n = n0 + wc + j * 16 + dcol;
        float bv_ = bias[n];
        int h = n >> 6, d = n & 63;
        ushort4 o;
        o.x = f2bf(acc[i][j][0] + bv_);
        o.y = f2bf(acc[i][j][1] + bv_);
        o.z = f2bf(acc[i][j][2] + bv_);
        o.w = f2bf(acc[i][j][3] + bv_);
        *reinterpret_cast<ushort4*>(C + ((size_t)(b * NH + h) * HD + d) * S_LEN + s) = o;
      }
    }
  }
}

// Output projection GEMM (fp32 rowmajor out), 128x64 tile, grid (32,16).
__global__ __launch_bounds__(256) void gemm_out(const unsigned short* __restrict__ A,
                                                const unsigned short* __restrict__ Bt,
                                                const float* __restrict__ bias,
                                                float* __restrict__ C) {
  constexpr int K = 1024;
  constexpr int N = 1024;
  __shared__ unsigned short Al[128 * 32];
  __shared__ unsigned short Bl[64 * 32];
  const int tid = threadIdx.x;
  const int w = tid >> 6, l = tid & 63;
  const int m0 = blockIdx.x * 128, n0 = blockIdx.y * 64;
  const int wr = (w >> 1) * 64, wc = (w & 1) * 32;
  const int lr = l & 15, lk = l >> 4;
  f32x4 acc[4][2] = {};
  for (int kt = 0; kt < K; kt += 32) {
#pragma unroll
    for (int i = 0; i < 2; ++i) {
      int seg = i * 256 + tid;
      int row = seg >> 2, ks = (seg & 3) * 8;
      load_lds16(A + (size_t)(m0 + row) * K + kt + ks, Al + seg * 8);
    }
    {
      int row = tid >> 2, ks = (tid & 3) * 8;
      load_lds16(Bt + (size_t)(n0 + row) * K + kt + ks, Bl + tid * 8);
    }
    __syncthreads();
    bf16x8 af[4], bfr[2];
#pragma unroll
    for (int t = 0; t < 4; ++t) af[t] = *(const bf16x8*)(Al + (wr + t * 16 + lr) * 32 + lk * 8);
#pragma unroll
    for (int t = 0; t < 2; ++t) bfr[t] = *(const bf16x8*)(Bl + (wc + t * 16 + lr) * 32 + lk * 8);
#pragma unroll
    for (int i = 0; i < 4; ++i)
#pragma unroll
      for (int j = 0; j < 2; ++j)
        acc[i][j] = __builtin_amdgcn_mfma_f32_16x16x32_bf16(af[i], bfr[j], acc[i][j], 0, 0, 0);
    __syncthreads();
  }
  const int drow = lk * 4, dcol = lr;
#pragma unroll
  for (int i = 0; i < 4; ++i)
#pragma unroll
    for (int j = 0; j < 2; ++j) {
      int n = n0 + wc + j * 16 + dcol;
      float bv = bias[n];
#pragma unroll
      for (int r = 0; r < 4; ++r) {
        int m = m0 + wr + i * 16 + drow + r;
        C[(size_t)m * N + n] = acc[i][j][r] + bv;
      }
    }
}

// ---------------------------------------------------------------------------
// Fused attention, R20 structure with the per-iteration inline-asm fences
// REMOVED (R21): all DS ops here are compiler-generated, so hipcc's own
// dependence tracking orders the may-aliasing LDS write->read pairs and
// inserts counted lgkmcnt before consumers; the explicit lgkmcnt(0)+
// sched_barrier(0) only pinned the schedule (rule #18 applies to inline-asm
// ds_reads, which we do not use). Everything else identical to R20.
// ---------------------------------------------------------------------------
#define STG_K128(T, BASE)                                                      \
  _Pragma("unroll") for (int i_ = 0; i_ < 2; ++i_) {                           \
    int s_ = i_ * 512 + tid;                                                   \
    int row_ = s_ >> 3, cb_ = (s_ & 7) * 16;                                   \
    load_lds16((const char*)Kbh + (size_t)((T) * 128 + row_) * 128 +           \
                   (cb_ ^ ((row_ & 7) << 4)),                                  \
               (BASE) + s_ * 16);                                              \
  }

#define STG_V128(T, BASE)                                                      \
  _Pragma("unroll") for (int i_ = 0; i_ < 2; ++i_) {                           \
    int s_ = i_ * 512 + tid;                                                   \
    int row_ = s_ >> 4, cb_ = (s_ & 15) * 16;                                  \
    load_lds16((const char*)Vbh + (size_t)row_ * 4096 + (T) * 256 +            \
                   (cb_ ^ ((row_ & 7) << 4)),                                  \
               (BASE) + s_ * 16);                                              \
  }

#define QKT4H(KPTR)                                                            \
  _Pragma("unroll") for (int st = 0; st < 4; ++st) {                           \
    const char* rp = (KPTR) + (st * 16 + lr) * 128;                            \
    bf16x8 k0 = *(const bf16x8*)(rp + a0);                                     \
    bf16x8 k1 = *(const bf16x8*)(rp + (a0 ^ 64));                              \
    f32x4 a = {};                                                              \
    a = __builtin_amdgcn_mfma_f32_16x16x32_bf16(k0, qf0, a, 0, 0, 0);          \
    a = __builtin_amdgcn_mfma_f32_16x16x32_bf16(k1, qf1, a, 0, 0, 0);          \
    acc[st] = a;                                                               \
  }

#define MASKADJ4(T)                                                            \
  _Pragma("unroll") for (int st = 0; st < 4; ++st) {                           \
    uchar4 m4 = *(const uchar4*)(mrow + (T) * 64 + st * 16 + lk * 4);          \
    if (m4.x) acc[st][0] = -8e9f;                                              \
    if (m4.y) acc[st][1] = -8e9f;                                              \
    if (m4.z) acc[st][2] = -8e9f;                                              \
    if (m4.w) acc[st][3] = -8e9f;                                              \
  }

#define MASK_PREPASS()                                                         \
  unsigned maskbits = 0;                                                       \
  _Pragma("unroll") for (int g4 = 0; g4 < 4; ++g4) {                           \
    unsigned mm[8];                                                            \
    const char* mp = (const char*)mrow + g4 * 512 + lk * 16;                   \
    _Pragma("unroll") for (int q8 = 0; q8 < 8; ++q8) {                         \
      u32x4 v = __builtin_nontemporal_load((const u32x4*)(mp + q8 * 64));      \
      mm[q8] = v.x | v.y | v.z | v.w;                                          \
    }                                                                          \
    _Pragma("unroll") for (int q8 = 0; q8 < 8; ++q8)                           \
      if (__any(mm[q8] != 0)) maskbits |= 1u << (g4 * 8 + q8);                 \
  }

__global__ __launch_bounds__(512, 4) void attn_fused_kernel(const unsigned short* __restrict__ Qh,
                                                            const unsigned short* __restrict__ Kh,
                                                            const unsigned short* __restrict__ Vt,
                                                            const unsigned char* __restrict__ mask,
                                                            float* __restrict__ attn_out,
                                                            unsigned short* __restrict__ ctx) {
  __shared__ char lds[81920];  // ph1: K 2x16KB @0, V 2x16KB @32768, Premap 8x2KB @65536
                               // ph2: per-wave 8KB P-store tiles @0 (64KB)
  char* const ldsK = lds;
  char* const ldsV = lds + 32768;
  const int tid = threadIdx.x;
  const int w = tid >> 6, l = tid & 63;
  const int lr = l & 15, lk = l >> 4;
  const int L = blockIdx.x;
  const int g = L & 7, j = L >> 3;
  const int bh = g * 4 + (j & 3);
  const int qt = j >> 2;
  const int q0w = qt * 128 + w * 16;
  const int b = bh >> 4, h = bh & 15;
  const unsigned short* Qbh = Qh + (size_t)bh * S_LEN * HD;
  const unsigned short* Kbh = Kh + (size_t)bh * S_LEN * HD;
  const unsigned short* Vbh = Vt + (size_t)bh * HD * S_LEN;
  const unsigned char* mrow = mask + (size_t)b * S_LEN * S_LEN + (size_t)(q0w + lr) * S_LEN;
  char* const abase = (char*)(attn_out + ((size_t)bh * S_LEN + q0w) * S_LEN);

  bf16x8 qf0 = *(const bf16x8*)(Qbh + (q0w + lr) * HD + lk * 8);
  bf16x8 qf1 = *(const bf16x8*)(Qbh + (q0w + lr) * HD + 32 + lk * 8);
  const int sw = (lr & 7) << 4;
  const int a0 = (lk * 16) ^ sw;
  const float sc = 0.125f;

  MASK_PREPASS()

  f32x4 acc[4];
  f32x4 cacc[4] = {};
  float tsum = 0.f;

  // ---- phase 1: lsum + unnormalized PV (KVBLK=128, 2-buffer staging) ----
  {
    STG_K128(0, ldsK)
    STG_V128(0, ldsV)
    char* const Pw = lds + 65536 + w * 2048;  // single per-wave buffer (16KB total)
    for (int T = 0; T < 16; ++T) {
      const int buf = T & 1;
      BAR();
      if (T < 15) {
        STG_K128(T + 1, ldsK + (buf ^ 1) * 16384)
        STG_V128(T + 1, ldsV + (buf ^ 1) * 16384)
      }
      if (T < 15) { VMCNT(4); } else { VMCNT(0); }
      BAR();
#pragma unroll
      for (int half = 0; half < 2; ++half) {
        const int t = 2 * T + half;
        const char* Kp = ldsK + buf * 16384 + half * 8192;
        const char* Vp = ldsV + buf * 16384;
        QKT4H(Kp)
        if (maskbits & (1u << t)) { MASKADJ4(t) }
        unsigned pk0[4], pk1[4];
#pragma unroll
        for (int st = 0; st < 4; ++st) {
          float p0 = __expf(acc[st][0] * sc);
          float p1 = __expf(acc[st][1] * sc);
          float p2 = __expf(acc[st][2] * sc);
          float p3 = __expf(acc[st][3] * sc);
          tsum += p0 + p1 + p2 + p3;
          pk0[st] = pack2bf(p0, p1);
          pk1[st] = pack2bf(p2, p3);
        }
#pragma unroll
        for (int st = 0; st < 4; ++st) {
          u32x2 pv;
          pv.x = pk0[st];
          pv.y = pk1[st];
          *(u32x2*)(Pw + lr * 128 + ((st * 32 + lk * 8) ^ sw)) = pv;
        }
        // no explicit fence: compiler orders the aliasing LDS write->read pair
#pragma unroll
        for (int c = 0; c < 2; ++c) {
          bf16x8 af = *(const bf16x8*)(Pw + lr * 128 + ((c * 64 + lk * 16) ^ sw));
          const int voff = (half * 128 + c * 64 + lk * 16) ^ sw;
#pragma unroll
          for (int dt = 0; dt < 4; ++dt) {
            bf16x8 vb = *(const bf16x8*)(Vp + (dt * 16 + lr) * 256 + voff);
            cacc[dt] = __builtin_amdgcn_mfma_f32_16x16x32_bf16(af, vb, cacc[dt], 0, 0, 0);
          }
        }
      }
    }
  }
  tsum += __shfl_xor(tsum, 16, 64);
  tsum += __shfl_xor(tsum, 32, 64);
  const float linv = 1.0f / tsum;

  // ctx (normalize here): lane (lr,lk) holds ctx[q=q0w+lk*4+r][d=dt*16+lr]
#pragma unroll
  for (int dt = 0; dt < 4; ++dt)
#pragma unroll
    for (int r = 0; r < 4; ++r)
      ctx[(size_t)(b * S_LEN + q0w + lk * 4 + r) * DM + h * HD + dt * 16 + lr] =
          f2bf(cacc[dt][r] * linv);

  // ---- phase 2: coalesced attn store (reuse staging LDS as per-wave tiles) --
  BAR();  // all waves done reading phase-1 LDS
  char* const Pw2 = lds + w * 8192;
  const int swp = lr << 4;
  for (int tt = 0; tt < 16; ++tt) {
#pragma unroll
    for (int half = 0; half < 2; ++half) {
      const int t = tt * 2 + half;
      bf16x8 kf0[4], kf1[4];
#pragma unroll
      for (int st = 0; st < 4; ++st) {
        const unsigned short* kp = Kbh + (size_t)(t * 64 + st * 16 + lr) * HD + lk * 8;
        kf0[st] = *(const bf16x8*)kp;
        kf1[st] = *(const bf16x8*)(kp + 32);
      }
#pragma unroll
      for (int st = 0; st < 4; ++st) {
        f32x4 a = {};
        a = __builtin_amdgcn_mfma_f32_16x16x32_bf16(kf0[st], qf0, a, 0, 0, 0);
        a = __builtin_amdgcn_mfma_f32_16x16x32_bf16(kf1[st], qf1, a, 0, 0, 0);
        acc[st] = a;
      }
      if (maskbits & (1u << t)) { MASKADJ4(t) }
      // P tile write: lane (lr,lk) holds row lr, bytes half*256+st*64+lk*16
#pragma unroll
      for (int st = 0; st < 4; ++st) {
        f32x4 p;
        p.x = __expf(acc[st][0] * sc) * linv;
        p.y = __expf(acc[st][1] * sc) * linv;
        p.z = __expf(acc[st][2] * sc) * linv;
        p.w = __expf(acc[st][3] * sc) * linv;
        *(f32x4*)(Pw2 + lr * 512 + ((half * 256 + st * 64 + lk * 16) ^ swp)) = p;
      }
    }
    // no explicit fence: compiler orders the aliasing LDS write->read pair
    // 8 coalesced NT stores: inst s covers rows {2s, 2s+1} x 512B contiguous.
#pragma unroll
    for (int s = 0; s < 8; ++s) {
      const int row = s * 2 + (l >> 5);
      const int ch = (l & 31) * 16;
      f32x4 v = *(const f32x4*)(Pw2 + row * 512 + (ch ^ (row << 4)));
      __builtin_nontemporal_store(v, (f32x4*)(abase + (size_t)row * 8192 + tt * 512 + ch));
    }
  }
}

// residual + LayerNorm: out = LN(pre + Qin) * gamma + beta, rows of 1024
__global__ __launch_bounds__(256) void ln_kernel(const float* __restrict__ pre,
                                                 const float* __restrict__ Qin,
                                                 const float* __restrict__ gamma,
                                                 const float* __restrict__ beta,
                                                 float* __restrict__ out) {
  __shared__ float red[4];
  const int row = blockIdx.x;
  const int tid = threadIdx.x;
  const int wv = tid >> 6, l = tid & 63;
  const float4 a = reinterpret_cast<const float4*>(pre + (size_t)row * DM)[tid];
  const float4 q = reinterpret_cast<const float4*>(Qin + (size_t)row * DM)[tid];
  float x0 = a.x + q.x, x1 = a.y + q.y, x2 = a.z + q.z, x3 = a.w + q.w;
  float s = x0 + x1 + x2 + x3;
#pragma unroll
  for (int off = 32; off >= 1; off >>= 1) s += __shfl_xor(s, off, 64);
  if (l == 0) red[wv] = s;
  __syncthreads();
  float mean = (red[0] + red[1] + red[2] + red[3]) * (1.0f / 1024.0f);
  __syncthreads();
  float d0 = x0 - mean, d1 = x1 - mean, d2 = x2 - mean, d3 = x3 - mean;
  float s2 = d0 * d0 + d1 * d1 + d2 * d2 + d3 * d3;
#pragma unroll
  for (int off = 32; off >= 1; off >>= 1) s2 += __shfl_xor(s2, off, 64);
  if (l == 0) red[wv] = s2;
  __syncthreads();
  float var = (red[0] + red[1] + red[2] + red[3]) * (1.0f / 1024.0f);
  float rstd = rsqrtf(var + 1e-5f);
  const float4 g = reinterpret_cast<const float4*>(gamma)[tid];
  const float4 bt = reinterpret_cast<const float4*>(beta)[tid];
  float4 o;
  o.x = d0 * rstd * g.x + bt.x;
  o.y = d1 * rstd * g.y + bt.y;
  o.z = d2 * rstd * g.z + bt.z;
  o.w = d3 * rstd * g.w + bt.w;
  reinterpret_cast<float4*>(out + (size_t)row * DM)[tid] = o;
}

extern "C" void kernel_launch(void* const* d_in, const int* in_sizes, int n_in,
                              void* d_out, int out_size, void* d_ws, size_t ws_size,
                              hipStream_t stream) {
  const float* Qi = (const float*)d_in[0];
  const float* Ki = (const float*)d_in[1];
  const float* Vi = (const float*)d_in[2];
  const unsigned char* mask = (const unsigned char*)d_in[3];
  const float* Wq = (const float*)d_in[4];
  const float* bq = (const float*)d_in[5];
  const float* Wk = (const float*)d_in[6];
  const float* bk = (const float*)d_in[7];
  const float* Wv = (const float*)d_in[8];
  const float* bv = (const float*)d_in[9];
  const float* Wo = (const float*)d_in[10];
  const float* bo = (const float*)d_in[11];
  const float* gamma = (const float*)d_in[12];
  const float* beta = (const float*)d_in[13];

  char* ws = (char*)d_ws;
  unsigned short* Qb = (unsigned short*)(ws);            // [4096][1024] bf16
  unsigned short* Kb = Qb + 4194304;
  unsigned short* Vb = Qb + 2 * 4194304;
  unsigned short* Wtq = (unsigned short*)(ws + 25165824);  // [n][k] bf16 x4
  unsigned short* Wtk = Wtq + 1048576;
  unsigned short* Wtv = Wtq + 2 * 1048576;
  unsigned short* Wto = Wtq + 3 * 1048576;
  unsigned short* Qhd = (unsigned short*)(ws + 33554432);  // [B,H,S,64] bf16
  unsigned short* Khd = (unsigned short*)(ws + 41943040);  // [B,H,S,64] bf16
  unsigned short* Vtd = (unsigned short*)(ws + 50331648);  // [B,H,64,S] bf16
  unsigned short* ctx = (unsigned short*)(ws);             // reuse Qb region
  float* preLN = (float*)(ws + 8388608);                   // reuse Kb/Vb region

  float* out0 = (float*)d_out;
  float* attn = out0 + 4194304;

  prep_kernel<<<16384, 256, 0, stream>>>(Qi, Ki, Vi, Qb, Kb, Vb,
                                         Wq, Wk, Wv, Wo, Wtq, Wtk, Wtv, Wto);
  dim3 gqkv(32, 8, 3);
  gemm_qkv<<<gqkv, 256, 0, stream>>>(Qb, Kb, Vb, Wtq, Wtk, Wtv,
                                     bq, bk, bv, Qhd, Khd, Vtd);
  attn_fused_kernel<<<512, 512, 0, stream>>>(Qhd, Khd, Vtd, mask, attn, ctx);
  dim3 gg(32, 16);
  gemm_out<<<gg, 256, 0, stream>>>(ctx, Wto, bo, preLN);
  ln_kernel<<<4096, 256, 0, stream>>>(preLN, Qi, gamma, beta, out0);
}